// Round 9
// baseline (895.057 us; speedup 1.0000x reference)
//
#include <hip/hip_runtime.h>
#include <hip/hip_bf16.h>
#include <math.h>

// MoE: T=65536 tokens, D=512, H=1024, E=8, TOP_K=2.
// R9: eg1/eg2 double-buffered 2-phase K-loop (issue next stage -> compute ->
// vmcnt(0)+s_barrier; 1 barrier/iter, loads hidden under MFMA). xcvt fused
// into gate_gemm1 (it already touches every x element).

typedef __attribute__((ext_vector_type(8))) short bf16x8;
typedef __attribute__((ext_vector_type(4))) float f32x4;

__device__ __forceinline__ unsigned short f2bf(float f){
  unsigned u = __builtin_bit_cast(unsigned, f);
  u += 0x7FFFu + ((u >> 16) & 1u);          // RNE
  return (unsigned short)(u >> 16);
}

__device__ __forceinline__ void gload16(const void* g, void* l){
  __builtin_amdgcn_global_load_lds((const __attribute__((address_space(1))) unsigned int*)g,
                                   (__attribute__((address_space(3))) unsigned int*)l, 16, 0, 0);
}

// ---------------------------------------------------------------------------
// Transpose + fp32->bf16 convert:  in [E][R][C] f32  ->  out [E][C][R] bf16
// ---------------------------------------------------------------------------
__global__ __launch_bounds__(256, 4)
void transpose_cvt_kernel(const float* __restrict__ in, unsigned short* __restrict__ out,
                          int R, int C){
  const int tilesR = R >> 6, tilesC = C >> 6;
  const int b = blockIdx.x;
  const int e = b / (tilesR * tilesC);
  const int rem = b % (tilesR * tilesC);
  const int rb = (rem / tilesC) << 6;
  const int cb = (rem % tilesC) << 6;
  const float* src = in + (size_t)e * R * C;
  unsigned short* dst = out + (size_t)e * R * C;
  __shared__ float t[64][65];
  const int r0 = threadIdx.x >> 4;
  const int c4 = (threadIdx.x & 15) << 2;
  #pragma unroll
  for (int p = 0; p < 4; ++p){
    int r = r0 + (p << 4);
    const float4 v = *(const float4*)(src + (size_t)(rb + r) * C + cb + c4);
    t[r][c4+0] = v.x; t[r][c4+1] = v.y; t[r][c4+2] = v.z; t[r][c4+3] = v.w;
  }
  __syncthreads();
  #pragma unroll
  for (int p = 0; p < 4; ++p){
    int cr = r0 + (p << 4);
    ushort4 o;
    o.x = f2bf(t[c4+0][cr]); o.y = f2bf(t[c4+1][cr]);
    o.z = f2bf(t[c4+2][cr]); o.w = f2bf(t[c4+3][cr]);
    *(ushort4*)(dst + (size_t)(cb + cr) * R + rb + c4) = o;
  }
}

// ---------------------------------------------------------------------------
// Gate GEMM1 (fp32, spill-proof) + fused x->bf16 conversion:
// h = relu(x @ gw1 + gb1) -> ghuf; xbf = bf16(x).
// ---------------------------------------------------------------------------
__global__ __launch_bounds__(512, 4)
void gate_gemm1_kernel(const float* __restrict__ x, const float* __restrict__ gw1,
                       const float* __restrict__ gb1, float* __restrict__ h,
                       unsigned short* __restrict__ xbf){
  __shared__ float xs[32][68];
  __shared__ float g1s[32][256];
  const int tid = threadIdx.x;
  const int t0 = blockIdx.x << 6;
  const int tg = tid >> 6;
  const int cg = tid & 63;

  const int xtok = tid >> 3, xk4 = (tid & 7) << 2;
  const int gr = tid >> 6, gc = (tid & 63) << 2;

  float acc0[4] = {0.f,0.f,0.f,0.f}, acc1[4] = {0.f,0.f,0.f,0.f};
  float acc2[4] = {0.f,0.f,0.f,0.f}, acc3[4] = {0.f,0.f,0.f,0.f};
  float acc4[4] = {0.f,0.f,0.f,0.f}, acc5[4] = {0.f,0.f,0.f,0.f};
  float acc6[4] = {0.f,0.f,0.f,0.f}, acc7[4] = {0.f,0.f,0.f,0.f};

  for (int kb = 0; kb < 512; kb += 32){
    __syncthreads();
    {
      const float4 v = *(const float4*)(x + (size_t)(t0 + xtok) * 512 + kb + xk4);
      xs[xk4+0][xtok] = v.x; xs[xk4+1][xtok] = v.y;
      xs[xk4+2][xtok] = v.z; xs[xk4+3][xtok] = v.w;
      ushort4 o;
      o.x = f2bf(v.x); o.y = f2bf(v.y); o.z = f2bf(v.z); o.w = f2bf(v.w);
      *(ushort4*)(xbf + (size_t)(t0 + xtok) * 512 + kb + xk4) = o;
    }
    #pragma unroll
    for (int p = 0; p < 4; ++p)
      *(float4*)&g1s[(p << 3) + gr][gc] =
        *(const float4*)(gw1 + (size_t)(kb + (p << 3) + gr) * 256 + gc);
    __syncthreads();
    #pragma unroll 4
    for (int k = 0; k < 32; ++k){
      const float4 wv = *(const float4*)&g1s[k][cg << 2];
      const float4 xa = *(const float4*)&xs[k][tg << 3];
      const float4 xb = *(const float4*)&xs[k][(tg << 3) + 4];
      acc0[0]=fmaf(xa.x,wv.x,acc0[0]); acc0[1]=fmaf(xa.x,wv.y,acc0[1]);
      acc0[2]=fmaf(xa.x,wv.z,acc0[2]); acc0[3]=fmaf(xa.x,wv.w,acc0[3]);
      acc1[0]=fmaf(xa.y,wv.x,acc1[0]); acc1[1]=fmaf(xa.y,wv.y,acc1[1]);
      acc1[2]=fmaf(xa.y,wv.z,acc1[2]); acc1[3]=fmaf(xa.y,wv.w,acc1[3]);
      acc2[0]=fmaf(xa.z,wv.x,acc2[0]); acc2[1]=fmaf(xa.z,wv.y,acc2[1]);
      acc2[2]=fmaf(xa.z,wv.z,acc2[2]); acc2[3]=fmaf(xa.z,wv.w,acc2[3]);
      acc3[0]=fmaf(xa.w,wv.x,acc3[0]); acc3[1]=fmaf(xa.w,wv.y,acc3[1]);
      acc3[2]=fmaf(xa.w,wv.z,acc3[2]); acc3[3]=fmaf(xa.w,wv.w,acc3[3]);
      acc4[0]=fmaf(xb.x,wv.x,acc4[0]); acc4[1]=fmaf(xb.x,wv.y,acc4[1]);
      acc4[2]=fmaf(xb.x,wv.z,acc4[2]); acc4[3]=fmaf(xb.x,wv.w,acc4[3]);
      acc5[0]=fmaf(xb.y,wv.x,acc5[0]); acc5[1]=fmaf(xb.y,wv.y,acc5[1]);
      acc5[2]=fmaf(xb.y,wv.z,acc5[2]); acc5[3]=fmaf(xb.y,wv.w,acc5[3]);
      acc6[0]=fmaf(xb.z,wv.x,acc6[0]); acc6[1]=fmaf(xb.z,wv.y,acc6[1]);
      acc6[2]=fmaf(xb.z,wv.z,acc6[2]); acc6[3]=fmaf(xb.z,wv.w,acc6[3]);
      acc7[0]=fmaf(xb.w,wv.x,acc7[0]); acc7[1]=fmaf(xb.w,wv.y,acc7[1]);
      acc7[2]=fmaf(xb.w,wv.z,acc7[2]); acc7[3]=fmaf(xb.w,wv.w,acc7[3]);
    }
  }

  const float4 bias = *(const float4*)(gb1 + (cg << 2));
  float* hp = h + (size_t)(t0 + (tg << 3)) * 256 + (cg << 2);
  float4 o;
  #define HOUT(ACC, T) \
    o.x = fmaxf(ACC[0] + bias.x, 0.f); o.y = fmaxf(ACC[1] + bias.y, 0.f); \
    o.z = fmaxf(ACC[2] + bias.z, 0.f); o.w = fmaxf(ACC[3] + bias.w, 0.f); \
    *(float4*)(hp + (size_t)(T) * 256) = o;
  HOUT(acc0, 0) HOUT(acc1, 1) HOUT(acc2, 2) HOUT(acc3, 3)
  HOUT(acc4, 4) HOUT(acc5, 5) HOUT(acc6, 6) HOUT(acc7, 7)
  #undef HOUT
}

// ---------------------------------------------------------------------------
// Gate2: logits, softmax, top2, re-softmax, block-aggregated scatter.
// ---------------------------------------------------------------------------
__global__ __launch_bounds__(256, 2)
void gate2_kernel(const float* __restrict__ h, const float* __restrict__ gw2,
                  const float* __restrict__ gb2,
                  int* __restrict__ counts, int* __restrict__ pair_tok,
                  float* __restrict__ pair_w){
  __shared__ float g2s[256 * 9];
  __shared__ int   lcnt[8];
  __shared__ int   lbase[8];
  __shared__ int   lpre[9];
  __shared__ int   ltok[8][256];
  __shared__ float lw[8][256];
  const int tid = threadIdx.x;
  const int t0 = blockIdx.x << 8;

  #pragma unroll
  for (int p = 0; p < 8; ++p){
    int idx = tid + (p << 8);
    g2s[(idx >> 3) * 9 + (idx & 7)] = gw2[idx];
  }
  if (tid < 8) lcnt[tid] = 0;
  __syncthreads();

  const int token = t0 + tid;
  float pl[8];
  #pragma unroll
  for (int e = 0; e < 8; ++e) pl[e] = gb2[e];
  for (int j = 0; j < 64; ++j){
    const float4 hv = *(const float4*)(h + (size_t)token * 256 + (j << 2));
    #pragma unroll
    for (int i = 0; i < 4; ++i){
      const float hx = ((const float*)&hv)[i];
      #pragma unroll
      for (int e = 0; e < 8; ++e)
        pl[e] = fmaf(hx, g2s[((j << 2) + i) * 9 + e], pl[e]);
    }
  }
  float m = pl[0];
  #pragma unroll
  for (int e = 1; e < 8; ++e) m = fmaxf(m, pl[e]);
  float p[8]; float s = 0.f;
  #pragma unroll
  for (int e = 0; e < 8; ++e){ p[e] = expf(pl[e] - m); s += p[e]; }
  float inv = 1.f / s;
  float m1 = -1.f, m2 = -1.f; int i1 = 0, i2 = 0;
  #pragma unroll
  for (int e = 0; e < 8; ++e){
    float pe = p[e] * inv;
    if (pe > m1){ m2 = m1; i2 = i1; m1 = pe; i1 = e; }
    else if (pe > m2){ m2 = pe; i2 = e; }
  }
  float e21 = expf(m2 - m1);
  float w1 = 1.f / (1.f + e21);
  float w2 = 1.f - w1;
  int p1 = atomicAdd(&lcnt[i1], 1); ltok[i1][p1] = token; lw[i1][p1] = w1;
  int p2 = atomicAdd(&lcnt[i2], 1); ltok[i2][p2] = token; lw[i2][p2] = w2;
  __syncthreads();
  if (tid < 8) lbase[tid] = atomicAdd(&counts[tid], lcnt[tid]);
  if (tid == 0){
    lpre[0] = 0;
    #pragma unroll
    for (int e = 0; e < 8; ++e) lpre[e+1] = lpre[e] + lcnt[e];
  }
  __syncthreads();
  const int total = lpre[8];
  for (int idx = tid; idx < total; idx += 256){
    int e = 0;
    #pragma unroll
    for (int q = 0; q < 7; ++q) e += (idx >= lpre[q + 1]) ? 1 : 0;
    const int i = idx - lpre[e];
    const int dst = (e << 16) + lbase[e] + i;
    pair_tok[dst] = ltok[e][i];
    pair_w[dst]   = lw[e][i];
  }
}

// ---------------------------------------------------------------------------
// Scan: chunk offsets (128-token chunks) + exact token prefix offsets.
// ---------------------------------------------------------------------------
__global__ void scan_kernel(const int* __restrict__ counts, int* __restrict__ offs,
                            int* __restrict__ toffs){
  if (threadIdx.x == 0){
    int o = 0, t = 0;
    #pragma unroll
    for (int e = 0; e < 8; ++e){
      offs[e] = o; o += (counts[e] + 127) >> 7;
      toffs[e] = t; t += counts[e];
    }
    offs[8] = o; toffs[8] = t;
  }
}

// ---------------------------------------------------------------------------
// eg1: h[seq][1024] = gelu(gather(x) @ we1 + be1), bf16.
// XCD-chunked swizzle; 2-phase dbuf (64KB LDS, 2 blocks/CU): issue stage of
// kb+1 into buf^1, compute buf, vmcnt(0)+s_barrier. Swapped MFMA operands
// (D rows = hcols regs, cols = tokens lanes) -> 8B h-stores.
// ---------------------------------------------------------------------------
__global__ __launch_bounds__(256, 2)
void eg1_kernel(const unsigned short* __restrict__ xbf,
                const unsigned short* __restrict__ we1T,   // [E][1024][512]
                const float* __restrict__ be1,
                const int* __restrict__ counts, const int* __restrict__ offs,
                const int* __restrict__ toffs, const int* __restrict__ pair_tok,
                unsigned short* __restrict__ h){
  const int g = (blockIdx.x & 7) * 1032 + (blockIdx.x >> 3);
  const int chunk = g >> 3, nt = g & 7;
  if (chunk >= offs[8]) return;
  int e = 0;
  #pragma unroll
  for (int q = 0; q < 7; ++q) e += (chunk >= offs[q+1]) ? 1 : 0;
  const int cnt = counts[e];
  const int base = (chunk - offs[e]) << 7;
  const int n0 = nt << 7;
  const int tid = threadIdx.x;
  const int lane = tid & 63;
  const int wv = tid >> 6;
  const int wr = wv >> 1, wc = wv & 1;
  const int lrow = lane & 15, kgrp = lane >> 4;

  __shared__ char lds[65536];            // [buf][A 16K | B 16K]

  const int srow = tid >> 3;
  const int sdelta = ((tid & 7) << 4) ^ ((srow & 7) << 4);
  unsigned aoff[4];
  #pragma unroll
  for (int i = 0; i < 4; ++i){
    int rr = base + srow + (i << 5);
    int tok = (rr < cnt) ? pair_tok[(e << 16) + rr] : 0;
    aoff[i] = ((unsigned)tok) << 10;
  }
  const char* const xb  = (const char*)xbf;
  const char* const w1b = (const char*)we1T + ((size_t)e << 20);

  f32x4 acc[4][4];                       // [hcol-frag][token-frag]
  #pragma unroll
  for (int i = 0; i < 4; ++i)
    #pragma unroll
    for (int j = 0; j < 4; ++j) acc[i][j] = (f32x4)0.f;

  auto stage = [&](int kb, char* dbase){
    #pragma unroll
    for (int i = 0; i < 4; ++i)
      gload16(xb + aoff[i] + (kb << 7) + sdelta, dbase + (tid << 4) + (i << 12));
    #pragma unroll
    for (int i = 0; i < 4; ++i)
      gload16(w1b + (size_t)(n0 + srow + (i << 5)) * 1024 + (kb << 7) + sdelta,
              dbase + 16384 + (tid << 4) + (i << 12));
  };

  const int sw = (lrow & 7) << 4;
  stage(0, lds);
  __syncthreads();
  int cur = 0;
  for (int kb = 0; kb < 8; ++kb){
    if (kb < 7) stage(kb + 1, lds + ((cur ^ 1) << 15));
    const char* const As = lds + (cur << 15);
    const char* const Bs = As + 16384;
    #pragma unroll
    for (int s = 0; s < 2; ++s){
      const int kbyte = ((s << 6) + (kgrp << 4)) ^ sw;
      bf16x8 af[4], bf[4];
      #pragma unroll
      for (int f = 0; f < 4; ++f){
        af[f] = *(const bf16x8*)(As + ((wr << 6) + (f << 4) + lrow) * 128 + kbyte);
        bf[f] = *(const bf16x8*)(Bs + ((wc << 6) + (f << 4) + lrow) * 128 + kbyte);
      }
      #pragma unroll
      for (int fb = 0; fb < 4; ++fb)
        #pragma unroll
        for (int fa = 0; fa < 4; ++fa)
          acc[fb][fa] = __builtin_amdgcn_mfma_f32_16x16x32_bf16(bf[fb], af[fa], acc[fb][fa], 0, 0, 0);
    }
    if (kb < 7){
      asm volatile("s_waitcnt vmcnt(0)" ::: "memory");
      __builtin_amdgcn_s_barrier();
    }
    cur ^= 1;
  }

  // epilogue: D[row=hcol][col=token]; 8B ushort4 stores.
  const int hrow0 = toffs[e] + base;
  float4 bias4[4];
  #pragma unroll
  for (int fb = 0; fb < 4; ++fb)
    bias4[fb] = *(const float4*)(be1 + (e << 10) + n0 + (wc << 6) + (fb << 4) + (kgrp << 2));
  #pragma unroll
  for (int fa = 0; fa < 4; ++fa){
    const int tl = (wr << 6) + (fa << 4) + lrow;
    if (base + tl < cnt){
      unsigned short* hp = h + (size_t)(hrow0 + tl) * 1024 + n0 + (wc << 6) + (kgrp << 2);
      #pragma unroll
      for (int fb = 0; fb < 4; ++fb){
        float v, gl; ushort4 o;
        v = acc[fb][fa][0] + bias4[fb].x; gl = 0.5f*v*(1.f+erff(v*0.70710678118654752f)); o.x = f2bf(gl);
        v = acc[fb][fa][1] + bias4[fb].y; gl = 0.5f*v*(1.f+erff(v*0.70710678118654752f)); o.y = f2bf(gl);
        v = acc[fb][fa][2] + bias4[fb].z; gl = 0.5f*v*(1.f+erff(v*0.70710678118654752f)); o.z = f2bf(gl);
        v = acc[fb][fa][3] + bias4[fb].w; gl = 0.5f*v*(1.f+erff(v*0.70710678118654752f)); o.w = f2bf(gl);
        *(ushort4*)(hp + (fb << 4)) = o;
      }
    }
  }
}

// ---------------------------------------------------------------------------
// eg2: out[tok] += w * (h @ we2 + be2). Same 2-phase dbuf; K=1024 (16 steps).
// ---------------------------------------------------------------------------
__global__ __launch_bounds__(256, 2)
void eg2_kernel(const unsigned short* __restrict__ h,
                const unsigned short* __restrict__ we2T,   // [E][512][1024]
                const float* __restrict__ be2,
                const int* __restrict__ counts, const int* __restrict__ offs,
                const int* __restrict__ toffs, const int* __restrict__ pair_tok,
                const float* __restrict__ pair_w,
                float* __restrict__ out){
  const int g = (blockIdx.x & 7) * 516 + (blockIdx.x >> 3);
  const int chunk = g >> 2, nt = g & 3;
  if (chunk >= offs[8]) return;
  int e = 0;
  #pragma unroll
  for (int q = 0; q < 7; ++q) e += (chunk >= offs[q+1]) ? 1 : 0;
  const int cnt = counts[e];
  const int base = (chunk - offs[e]) << 7;
  const int n0 = nt << 7;
  const int tid = threadIdx.x;
  const int lane = tid & 63;
  const int wv = tid >> 6;
  const int wr = wv >> 1, wc = wv & 1;
  const int lrow = lane & 15, kgrp = lane >> 4;

  __shared__ char lds[65536];

  const int srow = tid >> 3;
  const int sdelta = ((tid & 7) << 4) ^ ((srow & 7) << 4);
  const char* const hb  = (const char*)h + (size_t)(toffs[e] + base) * 2048;
  const char* const w2b = (const char*)we2T + ((size_t)e << 20);

  f32x4 acc[4][4];
  #pragma unroll
  for (int i = 0; i < 4; ++i)
    #pragma unroll
    for (int j = 0; j < 4; ++j) acc[i][j] = (f32x4)0.f;

  auto stage = [&](int kb, char* dbase){
    #pragma unroll
    for (int i = 0; i < 4; ++i)
      gload16(hb + (size_t)(srow + (i << 5)) * 2048 + (kb << 7) + sdelta,
              dbase + (tid << 4) + (i << 12));
    #pragma unroll
    for (int i = 0; i < 4; ++i)
      gload16(w2b + (size_t)(n0 + srow + (i << 5)) * 2048 + (kb << 7) + sdelta,
              dbase + 16384 + (tid << 4) + (i << 12));
  };

  const int sw = (lrow & 7) << 4;
  stage(0, lds);
  __syncthreads();
  int cur = 0;
  for (int kb = 0; kb < 16; ++kb){
    if (kb < 15) stage(kb + 1, lds + ((cur ^ 1) << 15));
    const char* const As = lds + (cur << 15);
    const char* const Bs = As + 16384;
    #pragma unroll
    for (int s = 0; s < 2; ++s){
      const int kbyte = ((s << 6) + (kgrp << 4)) ^ sw;
      bf16x8 af[4], bf[4];
      #pragma unroll
      for (int f = 0; f < 4; ++f){
        af[f] = *(const bf16x8*)(As + ((wr << 6) + (f << 4) + lrow) * 128 + kbyte);
        bf[f] = *(const bf16x8*)(Bs + ((wc << 6) + (f << 4) + lrow) * 128 + kbyte);
      }
      #pragma unroll
      for (int fr = 0; fr < 4; ++fr)
        #pragma unroll
        for (int fc = 0; fc < 4; ++fc)
          acc[fr][fc] = __builtin_amdgcn_mfma_f32_16x16x32_bf16(af[fr], bf[fc], acc[fr][fc], 0, 0, 0);
    }
    if (kb < 15){
      asm volatile("s_waitcnt vmcnt(0)" ::: "memory");
      __builtin_amdgcn_s_barrier();
    }
    cur ^= 1;
  }

  float bias2[4];
  #pragma unroll
  for (int fc = 0; fc < 4; ++fc)
    bias2[fc] = be2[(e << 9) + n0 + (wc << 6) + (fc << 4) + lrow];

  #pragma unroll
  for (int fr = 0; fr < 4; ++fr){
    #pragma unroll
    for (int rg = 0; rg < 4; ++rg){
      const int rloc = (wr << 6) + (fr << 4) + (kgrp << 2) + rg;
      const int r = base + rloc;
      if (r < cnt){
        const int tok = pair_tok[(e << 16) + r];
        const float wgt = pair_w[(e << 16) + r];
        float* const orow = out + (size_t)tok * 512 + n0 + (wc << 6) + lrow;
        #pragma unroll
        for (int fc = 0; fc < 4; ++fc)
          atomicAdd(orow + (fc << 4), wgt * (acc[fr][fc][rg] + bias2[fc]));
      }
    }
  }
}

// ---------------------------------------------------------------------------
extern "C" void kernel_launch(void* const* d_in, const int* in_sizes, int n_in,
                              void* d_out, int out_size, void* d_ws, size_t ws_size,
                              hipStream_t stream){
  const float* x   = (const float*)d_in[0];
  const float* gw1 = (const float*)d_in[1];
  const float* gb1 = (const float*)d_in[2];
  const float* gw2 = (const float*)d_in[3];
  const float* gb2 = (const float*)d_in[4];
  const float* we1 = (const float*)d_in[5];
  const float* be1 = (const float*)d_in[6];
  const float* we2 = (const float*)d_in[7];
  const float* be2 = (const float*)d_in[8];
  float* out = (float*)d_out;

  char* ws = (char*)d_ws;
  const size_t MiB = 1024 * 1024;
  unsigned short* we1T = (unsigned short*)(ws);                 // 8 MiB
  unsigned short* we2T = (unsigned short*)(ws + 8 * MiB);       // 8 MiB
  int*   pair_tok = (int*)  (ws + 16 * MiB);                    // 2 MiB
  float* pair_w   = (float*)(ws + 18 * MiB);                    // 2 MiB
  int*   counts   = (int*)  (ws + 20 * MiB);                    // 64 B
  int*   offs     = (int*)  (ws + 20 * MiB + 256);              // 64 B
  int*   toffs    = (int*)  (ws + 20 * MiB + 512);              // 64 B
  unsigned short* xbf  = (unsigned short*)(ws + 21 * MiB);      // 64 MiB
  float* ghuf          = (float*)(ws + 85 * MiB);               // 64 MiB (gate h)
  unsigned short* hexp = (unsigned short*)(ws + 85 * MiB);      // 257 MiB, aliases
                                                                // ghuf (stream-ordered)

  hipMemsetAsync(d_out, 0, (size_t)out_size * sizeof(float), stream);
  hipMemsetAsync(counts, 0, 256, stream);

  hipLaunchKernelGGL(transpose_cvt_kernel, dim3(1024), dim3(256), 0, stream,
                     we1, we1T, 512, 1024);
  hipLaunchKernelGGL(transpose_cvt_kernel, dim3(1024), dim3(256), 0, stream,
                     we2, we2T, 1024, 512);
  hipLaunchKernelGGL(gate_gemm1_kernel, dim3(1024), dim3(512), 0, stream,
                     x, gw1, gb1, ghuf, xbf);
  hipLaunchKernelGGL(gate2_kernel, dim3(256), dim3(256), 0, stream,
                     ghuf, gw2, gb2, counts, pair_tok, pair_w);
  hipLaunchKernelGGL(scan_kernel, dim3(1), dim3(64), 0, stream, counts, offs, toffs);

  hipLaunchKernelGGL(eg1_kernel, dim3(8256), dim3(256), 0, stream,
                     xbf, we1T, be1, counts, offs, toffs, pair_tok, hexp);
  hipLaunchKernelGGL(eg2_kernel, dim3(4128), dim3(256), 0, stream,
                     hexp, we2T, be2, counts, offs, toffs, pair_tok, pair_w, out);
}

// Round 10
// 706.430 us; speedup vs baseline: 1.2670x; 1.2670x over previous
//
#include <hip/hip_runtime.h>
#include <hip/hip_bf16.h>
#include <math.h>

// MoE: T=65536 tokens, D=512, H=1024, E=8, TOP_K=2.
// R10: eg1/eg2 reverted to R8 32KB/4-blocks structure (R9's dbuf halved
// occupancy and lost). eg2 epilogue de-atomicized: writes per-expert y rows
// (bf16, swapped-operand ushort4 stores) + combine kernel does the weighted
// token sum. Falls back to atomic epilogue if ws too small for ybuf.

typedef __attribute__((ext_vector_type(8))) short bf16x8;
typedef __attribute__((ext_vector_type(4))) float f32x4;

__device__ __forceinline__ unsigned short f2bf(float f){
  unsigned u = __builtin_bit_cast(unsigned, f);
  u += 0x7FFFu + ((u >> 16) & 1u);          // RNE
  return (unsigned short)(u >> 16);
}

__device__ __forceinline__ float bf2f(unsigned short u){
  return __builtin_bit_cast(float, (unsigned)u << 16);
}

__device__ __forceinline__ void gload16(const void* g, void* l){
  __builtin_amdgcn_global_load_lds((const __attribute__((address_space(1))) unsigned int*)g,
                                   (__attribute__((address_space(3))) unsigned int*)l, 16, 0, 0);
}

// ---------------------------------------------------------------------------
// Transpose + fp32->bf16 convert:  in [E][R][C] f32  ->  out [E][C][R] bf16
// ---------------------------------------------------------------------------
__global__ __launch_bounds__(256, 4)
void transpose_cvt_kernel(const float* __restrict__ in, unsigned short* __restrict__ out,
                          int R, int C){
  const int tilesR = R >> 6, tilesC = C >> 6;
  const int b = blockIdx.x;
  const int e = b / (tilesR * tilesC);
  const int rem = b % (tilesR * tilesC);
  const int rb = (rem / tilesC) << 6;
  const int cb = (rem % tilesC) << 6;
  const float* src = in + (size_t)e * R * C;
  unsigned short* dst = out + (size_t)e * R * C;
  __shared__ float t[64][65];
  const int r0 = threadIdx.x >> 4;
  const int c4 = (threadIdx.x & 15) << 2;
  #pragma unroll
  for (int p = 0; p < 4; ++p){
    int r = r0 + (p << 4);
    const float4 v = *(const float4*)(src + (size_t)(rb + r) * C + cb + c4);
    t[r][c4+0] = v.x; t[r][c4+1] = v.y; t[r][c4+2] = v.z; t[r][c4+3] = v.w;
  }
  __syncthreads();
  #pragma unroll
  for (int p = 0; p < 4; ++p){
    int cr = r0 + (p << 4);
    ushort4 o;
    o.x = f2bf(t[c4+0][cr]); o.y = f2bf(t[c4+1][cr]);
    o.z = f2bf(t[c4+2][cr]); o.w = f2bf(t[c4+3][cr]);
    *(ushort4*)(dst + (size_t)(cb + cr) * R + rb + c4) = o;
  }
}

// ---------------------------------------------------------------------------
// Gate GEMM1 (fp32, spill-proof) + fused x->bf16 conversion.
// ---------------------------------------------------------------------------
__global__ __launch_bounds__(512, 4)
void gate_gemm1_kernel(const float* __restrict__ x, const float* __restrict__ gw1,
                       const float* __restrict__ gb1, float* __restrict__ h,
                       unsigned short* __restrict__ xbf){
  __shared__ float xs[32][68];
  __shared__ float g1s[32][256];
  const int tid = threadIdx.x;
  const int t0 = blockIdx.x << 6;
  const int tg = tid >> 6;
  const int cg = tid & 63;

  const int xtok = tid >> 3, xk4 = (tid & 7) << 2;
  const int gr = tid >> 6, gc = (tid & 63) << 2;

  float acc0[4] = {0.f,0.f,0.f,0.f}, acc1[4] = {0.f,0.f,0.f,0.f};
  float acc2[4] = {0.f,0.f,0.f,0.f}, acc3[4] = {0.f,0.f,0.f,0.f};
  float acc4[4] = {0.f,0.f,0.f,0.f}, acc5[4] = {0.f,0.f,0.f,0.f};
  float acc6[4] = {0.f,0.f,0.f,0.f}, acc7[4] = {0.f,0.f,0.f,0.f};

  for (int kb = 0; kb < 512; kb += 32){
    __syncthreads();
    {
      const float4 v = *(const float4*)(x + (size_t)(t0 + xtok) * 512 + kb + xk4);
      xs[xk4+0][xtok] = v.x; xs[xk4+1][xtok] = v.y;
      xs[xk4+2][xtok] = v.z; xs[xk4+3][xtok] = v.w;
      ushort4 o;
      o.x = f2bf(v.x); o.y = f2bf(v.y); o.z = f2bf(v.z); o.w = f2bf(v.w);
      *(ushort4*)(xbf + (size_t)(t0 + xtok) * 512 + kb + xk4) = o;
    }
    #pragma unroll
    for (int p = 0; p < 4; ++p)
      *(float4*)&g1s[(p << 3) + gr][gc] =
        *(const float4*)(gw1 + (size_t)(kb + (p << 3) + gr) * 256 + gc);
    __syncthreads();
    #pragma unroll 4
    for (int k = 0; k < 32; ++k){
      const float4 wv = *(const float4*)&g1s[k][cg << 2];
      const float4 xa = *(const float4*)&xs[k][tg << 3];
      const float4 xb = *(const float4*)&xs[k][(tg << 3) + 4];
      acc0[0]=fmaf(xa.x,wv.x,acc0[0]); acc0[1]=fmaf(xa.x,wv.y,acc0[1]);
      acc0[2]=fmaf(xa.x,wv.z,acc0[2]); acc0[3]=fmaf(xa.x,wv.w,acc0[3]);
      acc1[0]=fmaf(xa.y,wv.x,acc1[0]); acc1[1]=fmaf(xa.y,wv.y,acc1[1]);
      acc1[2]=fmaf(xa.y,wv.z,acc1[2]); acc1[3]=fmaf(xa.y,wv.w,acc1[3]);
      acc2[0]=fmaf(xa.z,wv.x,acc2[0]); acc2[1]=fmaf(xa.z,wv.y,acc2[1]);
      acc2[2]=fmaf(xa.z,wv.z,acc2[2]); acc2[3]=fmaf(xa.z,wv.w,acc2[3]);
      acc3[0]=fmaf(xa.w,wv.x,acc3[0]); acc3[1]=fmaf(xa.w,wv.y,acc3[1]);
      acc3[2]=fmaf(xa.w,wv.z,acc3[2]); acc3[3]=fmaf(xa.w,wv.w,acc3[3]);
      acc4[0]=fmaf(xb.x,wv.x,acc4[0]); acc4[1]=fmaf(xb.x,wv.y,acc4[1]);
      acc4[2]=fmaf(xb.x,wv.z,acc4[2]); acc4[3]=fmaf(xb.x,wv.w,acc4[3]);
      acc5[0]=fmaf(xb.y,wv.x,acc5[0]); acc5[1]=fmaf(xb.y,wv.y,acc5[1]);
      acc5[2]=fmaf(xb.y,wv.z,acc5[2]); acc5[3]=fmaf(xb.y,wv.w,acc5[3]);
      acc6[0]=fmaf(xb.z,wv.x,acc6[0]); acc6[1]=fmaf(xb.z,wv.y,acc6[1]);
      acc6[2]=fmaf(xb.z,wv.z,acc6[2]); acc6[3]=fmaf(xb.z,wv.w,acc6[3]);
      acc7[0]=fmaf(xb.w,wv.x,acc7[0]); acc7[1]=fmaf(xb.w,wv.y,acc7[1]);
      acc7[2]=fmaf(xb.w,wv.z,acc7[2]); acc7[3]=fmaf(xb.w,wv.w,acc7[3]);
    }
  }

  const float4 bias = *(const float4*)(gb1 + (cg << 2));
  float* hp = h + (size_t)(t0 + (tg << 3)) * 256 + (cg << 2);
  float4 o;
  #define HOUT(ACC, T) \
    o.x = fmaxf(ACC[0] + bias.x, 0.f); o.y = fmaxf(ACC[1] + bias.y, 0.f); \
    o.z = fmaxf(ACC[2] + bias.z, 0.f); o.w = fmaxf(ACC[3] + bias.w, 0.f); \
    *(float4*)(hp + (size_t)(T) * 256) = o;
  HOUT(acc0, 0) HOUT(acc1, 1) HOUT(acc2, 2) HOUT(acc3, 3)
  HOUT(acc4, 4) HOUT(acc5, 5) HOUT(acc6, 6) HOUT(acc7, 7)
  #undef HOUT
}

// ---------------------------------------------------------------------------
// Gate2: logits, softmax, top2, re-softmax, block-aggregated scatter.
// Also records tpos[token*2 + {0,1}] = (e<<16)|list_pos for the combiner.
// ---------------------------------------------------------------------------
__global__ __launch_bounds__(256, 2)
void gate2_kernel(const float* __restrict__ h, const float* __restrict__ gw2,
                  const float* __restrict__ gb2,
                  int* __restrict__ counts, int* __restrict__ pair_tok,
                  float* __restrict__ pair_w, int* __restrict__ tpos){
  __shared__ float g2s[256 * 9];
  __shared__ int   lcnt[8];
  __shared__ int   lbase[8];
  __shared__ int   lpre[9];
  __shared__ int   ltok[8][256];
  __shared__ float lw[8][256];
  const int tid = threadIdx.x;
  const int t0 = blockIdx.x << 8;

  #pragma unroll
  for (int p = 0; p < 8; ++p){
    int idx = tid + (p << 8);
    g2s[(idx >> 3) * 9 + (idx & 7)] = gw2[idx];
  }
  if (tid < 8) lcnt[tid] = 0;
  __syncthreads();

  const int token = t0 + tid;
  float pl[8];
  #pragma unroll
  for (int e = 0; e < 8; ++e) pl[e] = gb2[e];
  for (int j = 0; j < 64; ++j){
    const float4 hv = *(const float4*)(h + (size_t)token * 256 + (j << 2));
    #pragma unroll
    for (int i = 0; i < 4; ++i){
      const float hx = ((const float*)&hv)[i];
      #pragma unroll
      for (int e = 0; e < 8; ++e)
        pl[e] = fmaf(hx, g2s[((j << 2) + i) * 9 + e], pl[e]);
    }
  }
  float m = pl[0];
  #pragma unroll
  for (int e = 1; e < 8; ++e) m = fmaxf(m, pl[e]);
  float p[8]; float s = 0.f;
  #pragma unroll
  for (int e = 0; e < 8; ++e){ p[e] = expf(pl[e] - m); s += p[e]; }
  float inv = 1.f / s;
  float m1 = -1.f, m2 = -1.f; int i1 = 0, i2 = 0;
  #pragma unroll
  for (int e = 0; e < 8; ++e){
    float pe = p[e] * inv;
    if (pe > m1){ m2 = m1; i2 = i1; m1 = pe; i1 = e; }
    else if (pe > m2){ m2 = pe; i2 = e; }
  }
  float e21 = expf(m2 - m1);
  float w1 = 1.f / (1.f + e21);
  float w2 = 1.f - w1;
  int p1 = atomicAdd(&lcnt[i1], 1); ltok[i1][p1] = token; lw[i1][p1] = w1;
  int p2 = atomicAdd(&lcnt[i2], 1); ltok[i2][p2] = token; lw[i2][p2] = w2;
  __syncthreads();
  if (tid < 8) lbase[tid] = atomicAdd(&counts[tid], lcnt[tid]);
  if (tid == 0){
    lpre[0] = 0;
    #pragma unroll
    for (int e = 0; e < 8; ++e) lpre[e+1] = lpre[e] + lcnt[e];
  }
  __syncthreads();
  tpos[(size_t)token * 2]     = (i1 << 16) + lbase[i1] + p1;
  tpos[(size_t)token * 2 + 1] = (i2 << 16) + lbase[i2] + p2;
  const int total = lpre[8];
  for (int idx = tid; idx < total; idx += 256){
    int e = 0;
    #pragma unroll
    for (int q = 0; q < 7; ++q) e += (idx >= lpre[q + 1]) ? 1 : 0;
    const int i = idx - lpre[e];
    const int dst = (e << 16) + lbase[e] + i;
    pair_tok[dst] = ltok[e][i];
    pair_w[dst]   = lw[e][i];
  }
}

// ---------------------------------------------------------------------------
// Scan: chunk offsets (128-token chunks) + exact token prefix offsets.
// ---------------------------------------------------------------------------
__global__ void scan_kernel(const int* __restrict__ counts, int* __restrict__ offs,
                            int* __restrict__ toffs){
  if (threadIdx.x == 0){
    int o = 0, t = 0;
    #pragma unroll
    for (int e = 0; e < 8; ++e){
      offs[e] = o; o += (counts[e] + 127) >> 7;
      toffs[e] = t; t += counts[e];
    }
    offs[8] = o; toffs[8] = t;
  }
}

// ---------------------------------------------------------------------------
// eg1 (R8 structure): h[seq][1024] = gelu(gather(x) @ we1 + be1), bf16.
// 32KB LDS, 4 blocks/CU, XCD-chunked swizzle, swapped MFMA operands.
// ---------------------------------------------------------------------------
__global__ __launch_bounds__(256, 4)
void eg1_kernel(const unsigned short* __restrict__ xbf,
                const unsigned short* __restrict__ we1T,   // [E][1024][512]
                const float* __restrict__ be1,
                const int* __restrict__ counts, const int* __restrict__ offs,
                const int* __restrict__ toffs, const int* __restrict__ pair_tok,
                unsigned short* __restrict__ h){
  const int g = (blockIdx.x & 7) * 1032 + (blockIdx.x >> 3);
  const int chunk = g >> 3, nt = g & 7;
  if (chunk >= offs[8]) return;
  int e = 0;
  #pragma unroll
  for (int q = 0; q < 7; ++q) e += (chunk >= offs[q+1]) ? 1 : 0;
  const int cnt = counts[e];
  const int base = (chunk - offs[e]) << 7;
  const int n0 = nt << 7;
  const int tid = threadIdx.x;
  const int lane = tid & 63;
  const int wv = tid >> 6;
  const int wr = wv >> 1, wc = wv & 1;
  const int lrow = lane & 15, kgrp = lane >> 4;

  __shared__ char lds[32768];
  char* const As = lds;
  char* const Bs = lds + 16384;

  const int srow = tid >> 3;
  const int sdelta = ((tid & 7) << 4) ^ ((srow & 7) << 4);
  unsigned aoff[4];
  #pragma unroll
  for (int i = 0; i < 4; ++i){
    int rr = base + srow + (i << 5);
    int tok = (rr < cnt) ? pair_tok[(e << 16) + rr] : 0;
    aoff[i] = ((unsigned)tok) << 10;
  }
  const char* const xb  = (const char*)xbf;
  const char* const w1b = (const char*)we1T + ((size_t)e << 20);

  f32x4 acc[4][4];                       // [hcol-frag][token-frag]
  #pragma unroll
  for (int i = 0; i < 4; ++i)
    #pragma unroll
    for (int j = 0; j < 4; ++j) acc[i][j] = (f32x4)0.f;

  const int sw = (lrow & 7) << 4;
  for (int kb = 0; kb < 8; ++kb){
    #pragma unroll
    for (int i = 0; i < 4; ++i)
      gload16(xb + aoff[i] + (kb << 7) + sdelta, As + (tid << 4) + (i << 12));
    #pragma unroll
    for (int i = 0; i < 4; ++i)
      gload16(w1b + (size_t)(n0 + srow + (i << 5)) * 1024 + (kb << 7) + sdelta,
              Bs + (tid << 4) + (i << 12));
    __syncthreads();
    #pragma unroll
    for (int s = 0; s < 2; ++s){
      const int kbyte = ((s << 6) + (kgrp << 4)) ^ sw;
      bf16x8 af[4], bf[4];
      #pragma unroll
      for (int f = 0; f < 4; ++f){
        af[f] = *(const bf16x8*)(As + ((wr << 6) + (f << 4) + lrow) * 128 + kbyte);
        bf[f] = *(const bf16x8*)(Bs + ((wc << 6) + (f << 4) + lrow) * 128 + kbyte);
      }
      #pragma unroll
      for (int fb = 0; fb < 4; ++fb)
        #pragma unroll
        for (int fa = 0; fa < 4; ++fa)
          acc[fb][fa] = __builtin_amdgcn_mfma_f32_16x16x32_bf16(bf[fb], af[fa], acc[fb][fa], 0, 0, 0);
    }
    __syncthreads();
  }

  const int hrow0 = toffs[e] + base;
  float4 bias4[4];
  #pragma unroll
  for (int fb = 0; fb < 4; ++fb)
    bias4[fb] = *(const float4*)(be1 + (e << 10) + n0 + (wc << 6) + (fb << 4) + (kgrp << 2));
  #pragma unroll
  for (int fa = 0; fa < 4; ++fa){
    const int tl = (wr << 6) + (fa << 4) + lrow;
    if (base + tl < cnt){
      unsigned short* hp = h + (size_t)(hrow0 + tl) * 1024 + n0 + (wc << 6) + (kgrp << 2);
      #pragma unroll
      for (int fb = 0; fb < 4; ++fb){
        float v, gl; ushort4 o;
        v = acc[fb][fa][0] + bias4[fb].x; gl = 0.5f*v*(1.f+erff(v*0.70710678118654752f)); o.x = f2bf(gl);
        v = acc[fb][fa][1] + bias4[fb].y; gl = 0.5f*v*(1.f+erff(v*0.70710678118654752f)); o.y = f2bf(gl);
        v = acc[fb][fa][2] + bias4[fb].z; gl = 0.5f*v*(1.f+erff(v*0.70710678118654752f)); o.z = f2bf(gl);
        v = acc[fb][fa][3] + bias4[fb].w; gl = 0.5f*v*(1.f+erff(v*0.70710678118654752f)); o.w = f2bf(gl);
        *(ushort4*)(hp + (fb << 4)) = o;
      }
    }
  }
}

// ---------------------------------------------------------------------------
// eg2 (R8 structure, swapped operands): y = h @ we2 + be2.
// ybuf path: plain bf16 ushort4 stores (no atomics). Fallback: atomics to out.
// ---------------------------------------------------------------------------
__global__ __launch_bounds__(256, 4)
void eg2_kernel(const unsigned short* __restrict__ h,
                const unsigned short* __restrict__ we2T,   // [E][512][1024]
                const float* __restrict__ be2,
                const int* __restrict__ counts, const int* __restrict__ offs,
                const int* __restrict__ toffs, const int* __restrict__ pair_tok,
                const float* __restrict__ pair_w,
                unsigned short* __restrict__ ybuf,         // may be null
                float* __restrict__ out){
  const int g = (blockIdx.x & 7) * 516 + (blockIdx.x >> 3);
  const int chunk = g >> 2, nt = g & 3;
  if (chunk >= offs[8]) return;
  int e = 0;
  #pragma unroll
  for (int q = 0; q < 7; ++q) e += (chunk >= offs[q+1]) ? 1 : 0;
  const int cnt = counts[e];
  const int base = (chunk - offs[e]) << 7;
  const int n0 = nt << 7;
  const int tid = threadIdx.x;
  const int lane = tid & 63;
  const int wv = tid >> 6;
  const int wr = wv >> 1, wc = wv & 1;
  const int lrow = lane & 15, kgrp = lane >> 4;

  __shared__ char lds[32768];
  char* const As = lds;
  char* const Bs = lds + 16384;

  const int srow = tid >> 3;
  const int sdelta = ((tid & 7) << 4) ^ ((srow & 7) << 4);
  const char* const hb  = (const char*)h + (size_t)(toffs[e] + base) * 2048;
  const char* const w2b = (const char*)we2T + ((size_t)e << 20);

  f32x4 acc[4][4];                       // [outcol-frag][token-frag]
  #pragma unroll
  for (int i = 0; i < 4; ++i)
    #pragma unroll
    for (int j = 0; j < 4; ++j) acc[i][j] = (f32x4)0.f;

  const int sw = (lrow & 7) << 4;
  for (int kb = 0; kb < 16; ++kb){
    #pragma unroll
    for (int i = 0; i < 4; ++i)
      gload16(hb + (size_t)(srow + (i << 5)) * 2048 + (kb << 7) + sdelta,
              As + (tid << 4) + (i << 12));
    #pragma unroll
    for (int i = 0; i < 4; ++i)
      gload16(w2b + (size_t)(n0 + srow + (i << 5)) * 2048 + (kb << 7) + sdelta,
              Bs + (tid << 4) + (i << 12));
    __syncthreads();
    #pragma unroll
    for (int s = 0; s < 2; ++s){
      const int kbyte = ((s << 6) + (kgrp << 4)) ^ sw;
      bf16x8 af[4], bf[4];
      #pragma unroll
      for (int f = 0; f < 4; ++f){
        af[f] = *(const bf16x8*)(As + ((wr << 6) + (f << 4) + lrow) * 128 + kbyte);
        bf[f] = *(const bf16x8*)(Bs + ((wc << 6) + (f << 4) + lrow) * 128 + kbyte);
      }
      #pragma unroll
      for (int fb = 0; fb < 4; ++fb)
        #pragma unroll
        for (int fa = 0; fa < 4; ++fa)
          acc[fb][fa] = __builtin_amdgcn_mfma_f32_16x16x32_bf16(bf[fb], af[fa], acc[fb][fa], 0, 0, 0);
    }
    __syncthreads();
  }

  float4 bias4[4];
  #pragma unroll
  for (int fb = 0; fb < 4; ++fb)
    bias4[fb] = *(const float4*)(be2 + (e << 9) + n0 + (wc << 6) + (fb << 4) + (kgrp << 2));

  if (ybuf){
    const int yrow0 = toffs[e] + base;
    #pragma unroll
    for (int fa = 0; fa < 4; ++fa){
      const int tl = (wr << 6) + (fa << 4) + lrow;
      if (base + tl < cnt){
        unsigned short* yp = ybuf + (size_t)(yrow0 + tl) * 512 + n0 + (wc << 6) + (kgrp << 2);
        #pragma unroll
        for (int fb = 0; fb < 4; ++fb){
          ushort4 o;
          o.x = f2bf(acc[fb][fa][0] + bias4[fb].x);
          o.y = f2bf(acc[fb][fa][1] + bias4[fb].y);
          o.z = f2bf(acc[fb][fa][2] + bias4[fb].z);
          o.w = f2bf(acc[fb][fa][3] + bias4[fb].w);
          *(ushort4*)(yp + (fb << 4)) = o;
        }
      }
    }
  } else {
    #pragma unroll
    for (int fa = 0; fa < 4; ++fa){
      const int tl = (wr << 6) + (fa << 4) + lrow;
      const int r = base + tl;
      if (r < cnt){
        const int tok = pair_tok[(e << 16) + r];
        const float wgt = pair_w[(e << 16) + r];
        float* const orow = out + (size_t)tok * 512 + n0 + (wc << 6) + (kgrp << 2);
        #pragma unroll
        for (int fb = 0; fb < 4; ++fb){
          atomicAdd(orow + (fb << 4) + 0, wgt * (acc[fb][fa][0] + bias4[fb].x));
          atomicAdd(orow + (fb << 4) + 1, wgt * (acc[fb][fa][1] + bias4[fb].y));
          atomicAdd(orow + (fb << 4) + 2, wgt * (acc[fb][fa][2] + bias4[fb].z));
          atomicAdd(orow + (fb << 4) + 3, wgt * (acc[fb][fa][3] + bias4[fb].w));
        }
      }
    }
  }
}

// ---------------------------------------------------------------------------
// Combine: out[t] = w0 * y[seq0] + w1 * y[seq1].  One 64-lane group per
// token; lane owns 8 cols (16B y-loads per row, 32B out store).
// ---------------------------------------------------------------------------
__global__ __launch_bounds__(256, 8)
void combine_kernel(const unsigned short* __restrict__ ybuf,
                    const int* __restrict__ tpos, const int* __restrict__ toffs,
                    const float* __restrict__ pair_w,
                    float* __restrict__ out){
  const int wg = threadIdx.x >> 6;
  const int lane = threadIdx.x & 63;
  for (int t = (blockIdx.x << 2) + wg; t < 65536; t += 4096 * 4){
    const int d0 = tpos[(size_t)t * 2];
    const int d1 = tpos[(size_t)t * 2 + 1];
    const int seq0 = toffs[d0 >> 16] + (d0 & 0xFFFF);
    const int seq1 = toffs[d1 >> 16] + (d1 & 0xFFFF);
    const float w0 = pair_w[d0];
    const float w1 = pair_w[d1];
    const bf16x8 a = *(const bf16x8*)(ybuf + (size_t)seq0 * 512 + (lane << 3));
    const bf16x8 b = *(const bf16x8*)(ybuf + (size_t)seq1 * 512 + (lane << 3));
    float4 o0, o1;
    o0.x = w0*bf2f((unsigned short)a[0]) + w1*bf2f((unsigned short)b[0]);
    o0.y = w0*bf2f((unsigned short)a[1]) + w1*bf2f((unsigned short)b[1]);
    o0.z = w0*bf2f((unsigned short)a[2]) + w1*bf2f((unsigned short)b[2]);
    o0.w = w0*bf2f((unsigned short)a[3]) + w1*bf2f((unsigned short)b[3]);
    o1.x = w0*bf2f((unsigned short)a[4]) + w1*bf2f((unsigned short)b[4]);
    o1.y = w0*bf2f((unsigned short)a[5]) + w1*bf2f((unsigned short)b[5]);
    o1.z = w0*bf2f((unsigned short)a[6]) + w1*bf2f((unsigned short)b[6]);
    o1.w = w0*bf2f((unsigned short)a[7]) + w1*bf2f((unsigned short)b[7]);
    float* op = out + (size_t)t * 512 + (lane << 3);
    *(float4*)op = o0;
    *(float4*)(op + 4) = o1;
  }
}

// ---------------------------------------------------------------------------
extern "C" void kernel_launch(void* const* d_in, const int* in_sizes, int n_in,
                              void* d_out, int out_size, void* d_ws, size_t ws_size,
                              hipStream_t stream){
  const float* x   = (const float*)d_in[0];
  const float* gw1 = (const float*)d_in[1];
  const float* gb1 = (const float*)d_in[2];
  const float* gw2 = (const float*)d_in[3];
  const float* gb2 = (const float*)d_in[4];
  const float* we1 = (const float*)d_in[5];
  const float* be1 = (const float*)d_in[6];
  const float* we2 = (const float*)d_in[7];
  const float* be2 = (const float*)d_in[8];
  float* out = (float*)d_out;

  char* ws = (char*)d_ws;
  const size_t MiB = 1024 * 1024;
  unsigned short* we1T = (unsigned short*)(ws);                 // 8 MiB
  unsigned short* we2T = (unsigned short*)(ws + 8 * MiB);       // 8 MiB
  int*   pair_tok = (int*)  (ws + 16 * MiB);                    // 2 MiB
  float* pair_w   = (float*)(ws + 18 * MiB);                    // 2 MiB
  int*   counts   = (int*)  (ws + 20 * MiB);                    // 64 B
  int*   offs     = (int*)  (ws + 20 * MiB + 256);              // 64 B
  int*   toffs    = (int*)  (ws + 20 * MiB + 512);              // 64 B
  int*   tpos     = (int*)  (ws + 20 * MiB + 4096);             // 512 KiB
  unsigned short* xbf  = (unsigned short*)(ws + 21 * MiB);      // 64 MiB
  float* ghuf          = (float*)(ws + 85 * MiB);               // 64 MiB (gate h)
  unsigned short* hexp = (unsigned short*)(ws + 85 * MiB);      // 256 MiB, aliases ghuf
  unsigned short* ybuf = (unsigned short*)(ws + 341 * MiB);     // 128 MiB
  const bool have_y = ws_size >= 470 * MiB;

  if (!have_y)
    hipMemsetAsync(d_out, 0, (size_t)out_size * sizeof(float), stream);
  hipMemsetAsync(counts, 0, 256, stream);

  hipLaunchKernelGGL(transpose_cvt_kernel, dim3(1024), dim3(256), 0, stream,
                     we1, we1T, 512, 1024);
  hipLaunchKernelGGL(transpose_cvt_kernel, dim3(1024), dim3(256), 0, stream,
                     we2, we2T, 1024, 512);
  hipLaunchKernelGGL(gate_gemm1_kernel, dim3(1024), dim3(512), 0, stream,
                     x, gw1, gb1, ghuf, xbf);
  hipLaunchKernelGGL(gate2_kernel, dim3(256), dim3(256), 0, stream,
                     ghuf, gw2, gb2, counts, pair_tok, pair_w, tpos);
  hipLaunchKernelGGL(scan_kernel, dim3(1), dim3(64), 0, stream, counts, offs, toffs);

  hipLaunchKernelGGL(eg1_kernel, dim3(8256), dim3(256), 0, stream,
                     xbf, we1T, be1, counts, offs, toffs, pair_tok, hexp);
  hipLaunchKernelGGL(eg2_kernel, dim3(4128), dim3(256), 0, stream,
                     hexp, we2T, be2, counts, offs, toffs, pair_tok, pair_w,
                     have_y ? ybuf : (unsigned short*)nullptr, out);
  if (have_y)
    hipLaunchKernelGGL(combine_kernel, dim3(4096), dim3(256), 0, stream,
                       ybuf, tpos, toffs, pair_w, out);
}

// Round 11
// 696.911 us; speedup vs baseline: 1.2843x; 1.0137x over previous
//
#include <hip/hip_runtime.h>
#include <hip/hip_bf16.h>
#include <math.h>

// MoE: T=65536 tokens, D=512, H=1024, E=8, TOP_K=2.
// R11: gate_gemm1 thread tile 8x4 -> 16x4 (64 acc, 93% FMA density; gate must
// stay fp32 for top-2 selection fidelity). Rest identical to R10 (split
// grouped-GEMM experts, de-atomicized eg2 + combine, XCD-chunked swizzle).

typedef __attribute__((ext_vector_type(8))) short bf16x8;
typedef __attribute__((ext_vector_type(4))) float f32x4;

__device__ __forceinline__ unsigned short f2bf(float f){
  unsigned u = __builtin_bit_cast(unsigned, f);
  u += 0x7FFFu + ((u >> 16) & 1u);          // RNE
  return (unsigned short)(u >> 16);
}

__device__ __forceinline__ float bf2f(unsigned short u){
  return __builtin_bit_cast(float, (unsigned)u << 16);
}

__device__ __forceinline__ void gload16(const void* g, void* l){
  __builtin_amdgcn_global_load_lds((const __attribute__((address_space(1))) unsigned int*)g,
                                   (__attribute__((address_space(3))) unsigned int*)l, 16, 0, 0);
}

// ---------------------------------------------------------------------------
// Transpose + fp32->bf16 convert:  in [E][R][C] f32  ->  out [E][C][R] bf16
// ---------------------------------------------------------------------------
__global__ __launch_bounds__(256, 4)
void transpose_cvt_kernel(const float* __restrict__ in, unsigned short* __restrict__ out,
                          int R, int C){
  const int tilesR = R >> 6, tilesC = C >> 6;
  const int b = blockIdx.x;
  const int e = b / (tilesR * tilesC);
  const int rem = b % (tilesR * tilesC);
  const int rb = (rem / tilesC) << 6;
  const int cb = (rem % tilesC) << 6;
  const float* src = in + (size_t)e * R * C;
  unsigned short* dst = out + (size_t)e * R * C;
  __shared__ float t[64][65];
  const int r0 = threadIdx.x >> 4;
  const int c4 = (threadIdx.x & 15) << 2;
  #pragma unroll
  for (int p = 0; p < 4; ++p){
    int r = r0 + (p << 4);
    const float4 v = *(const float4*)(src + (size_t)(rb + r) * C + cb + c4);
    t[r][c4+0] = v.x; t[r][c4+1] = v.y; t[r][c4+2] = v.z; t[r][c4+3] = v.w;
  }
  __syncthreads();
  #pragma unroll
  for (int p = 0; p < 4; ++p){
    int cr = r0 + (p << 4);
    ushort4 o;
    o.x = f2bf(t[c4+0][cr]); o.y = f2bf(t[c4+1][cr]);
    o.z = f2bf(t[c4+2][cr]); o.w = f2bf(t[c4+3][cr]);
    *(ushort4*)(dst + (size_t)(cb + cr) * R + rb + c4) = o;
  }
}

// ---------------------------------------------------------------------------
// Gate GEMM1 (fp32) + fused x->bf16: h = relu(x @ gw1 + gb1); xbf = bf16(x).
// 1024 blocks x 256 thr x 64 tokens. Thread (tg=tid>>6, cg=tid&63):
// 16 tokens x 4 cols = 64 acc. Per k: 1 conflict-free g1s float4 (64 lanes
// contiguous 1KB) + 4 wave-uniform xs broadcasts -> 64 FMA / 5 reads.
// ---------------------------------------------------------------------------
__global__ __launch_bounds__(256, 3)
void gate_gemm1_kernel(const float* __restrict__ x, const float* __restrict__ gw1,
                       const float* __restrict__ gb1, float* __restrict__ h,
                       unsigned short* __restrict__ xbf){
  __shared__ float xs[32][68];          // [k][tok]
  __shared__ float g1s[32][256];        // [k][col]
  const int tid = threadIdx.x;
  const int t0 = blockIdx.x << 6;
  const int tg = tid >> 6;              // wave id: tokens tg*16..+15
  const int cg = tid & 63;              // cols 4cg..4cg+3

  const int xtok = tid >> 2, xk8 = (tid & 3) << 3;   // x stage: 8 floats/thread

  float acc[16][4];
  #pragma unroll
  for (int t = 0; t < 16; ++t)
    #pragma unroll
    for (int c = 0; c < 4; ++c) acc[t][c] = 0.f;

  for (int kb = 0; kb < 512; kb += 32){
    __syncthreads();
    { // stage x: 64 tok x 32 k (2 float4/thread), fused bf16 emit
      const float4 v0 = *(const float4*)(x + (size_t)(t0 + xtok) * 512 + kb + xk8);
      const float4 v1 = *(const float4*)(x + (size_t)(t0 + xtok) * 512 + kb + xk8 + 4);
      xs[xk8+0][xtok] = v0.x; xs[xk8+1][xtok] = v0.y;
      xs[xk8+2][xtok] = v0.z; xs[xk8+3][xtok] = v0.w;
      xs[xk8+4][xtok] = v1.x; xs[xk8+5][xtok] = v1.y;
      xs[xk8+6][xtok] = v1.z; xs[xk8+7][xtok] = v1.w;
      ushort4 o0, o1;
      o0.x = f2bf(v0.x); o0.y = f2bf(v0.y); o0.z = f2bf(v0.z); o0.w = f2bf(v0.w);
      o1.x = f2bf(v1.x); o1.y = f2bf(v1.y); o1.z = f2bf(v1.z); o1.w = f2bf(v1.w);
      *(ushort4*)(xbf + (size_t)(t0 + xtok) * 512 + kb + xk8)     = o0;
      *(ushort4*)(xbf + (size_t)(t0 + xtok) * 512 + kb + xk8 + 4) = o1;
    }
    #pragma unroll
    for (int p = 0; p < 8; ++p){        // stage gw1: 32 k x 256 col
      int f = tid + (p << 8);
      int r = f >> 6, c4 = (f & 63) << 2;
      *(float4*)&g1s[r][c4] = *(const float4*)(gw1 + (size_t)(kb + r) * 256 + c4);
    }
    __syncthreads();
    #pragma unroll 4
    for (int k = 0; k < 32; ++k){
      const float4 wv = *(const float4*)&g1s[k][cg << 2];
      const float4 xq0 = *(const float4*)&xs[k][(tg << 4) + 0];
      const float4 xq1 = *(const float4*)&xs[k][(tg << 4) + 4];
      const float4 xq2 = *(const float4*)&xs[k][(tg << 4) + 8];
      const float4 xq3 = *(const float4*)&xs[k][(tg << 4) + 12];
      #define FMA4(T, XV) \
        acc[T][0] = fmaf(XV, wv.x, acc[T][0]); acc[T][1] = fmaf(XV, wv.y, acc[T][1]); \
        acc[T][2] = fmaf(XV, wv.z, acc[T][2]); acc[T][3] = fmaf(XV, wv.w, acc[T][3]);
      FMA4(0,  xq0.x) FMA4(1,  xq0.y) FMA4(2,  xq0.z) FMA4(3,  xq0.w)
      FMA4(4,  xq1.x) FMA4(5,  xq1.y) FMA4(6,  xq1.z) FMA4(7,  xq1.w)
      FMA4(8,  xq2.x) FMA4(9,  xq2.y) FMA4(10, xq2.z) FMA4(11, xq2.w)
      FMA4(12, xq3.x) FMA4(13, xq3.y) FMA4(14, xq3.z) FMA4(15, xq3.w)
      #undef FMA4
    }
  }

  const float4 bias = *(const float4*)(gb1 + (cg << 2));
  float* hp = h + (size_t)(t0 + (tg << 4)) * 256 + (cg << 2);
  #pragma unroll
  for (int t = 0; t < 16; ++t){
    float4 o;
    o.x = fmaxf(acc[t][0] + bias.x, 0.f);
    o.y = fmaxf(acc[t][1] + bias.y, 0.f);
    o.z = fmaxf(acc[t][2] + bias.z, 0.f);
    o.w = fmaxf(acc[t][3] + bias.w, 0.f);
    *(float4*)(hp + (size_t)t * 256) = o;
  }
}

// ---------------------------------------------------------------------------
// Gate2: logits, softmax, top2, re-softmax, block-aggregated scatter.
// Records tpos[token*2 + {0,1}] = (e<<16)|list_pos for the combiner.
// ---------------------------------------------------------------------------
__global__ __launch_bounds__(256, 2)
void gate2_kernel(const float* __restrict__ h, const float* __restrict__ gw2,
                  const float* __restrict__ gb2,
                  int* __restrict__ counts, int* __restrict__ pair_tok,
                  float* __restrict__ pair_w, int* __restrict__ tpos){
  __shared__ float g2s[256 * 9];
  __shared__ int   lcnt[8];
  __shared__ int   lbase[8];
  __shared__ int   lpre[9];
  __shared__ int   ltok[8][256];
  __shared__ float lw[8][256];
  const int tid = threadIdx.x;
  const int t0 = blockIdx.x << 8;

  #pragma unroll
  for (int p = 0; p < 8; ++p){
    int idx = tid + (p << 8);
    g2s[(idx >> 3) * 9 + (idx & 7)] = gw2[idx];
  }
  if (tid < 8) lcnt[tid] = 0;
  __syncthreads();

  const int token = t0 + tid;
  float pl[8];
  #pragma unroll
  for (int e = 0; e < 8; ++e) pl[e] = gb2[e];
  for (int j = 0; j < 64; ++j){
    const float4 hv = *(const float4*)(h + (size_t)token * 256 + (j << 2));
    #pragma unroll
    for (int i = 0; i < 4; ++i){
      const float hx = ((const float*)&hv)[i];
      #pragma unroll
      for (int e = 0; e < 8; ++e)
        pl[e] = fmaf(hx, g2s[((j << 2) + i) * 9 + e], pl[e]);
    }
  }
  float m = pl[0];
  #pragma unroll
  for (int e = 1; e < 8; ++e) m = fmaxf(m, pl[e]);
  float p[8]; float s = 0.f;
  #pragma unroll
  for (int e = 0; e < 8; ++e){ p[e] = expf(pl[e] - m); s += p[e]; }
  float inv = 1.f / s;
  float m1 = -1.f, m2 = -1.f; int i1 = 0, i2 = 0;
  #pragma unroll
  for (int e = 0; e < 8; ++e){
    float pe = p[e] * inv;
    if (pe > m1){ m2 = m1; i2 = i1; m1 = pe; i1 = e; }
    else if (pe > m2){ m2 = pe; i2 = e; }
  }
  float e21 = expf(m2 - m1);
  float w1 = 1.f / (1.f + e21);
  float w2 = 1.f - w1;
  int p1 = atomicAdd(&lcnt[i1], 1); ltok[i1][p1] = token; lw[i1][p1] = w1;
  int p2 = atomicAdd(&lcnt[i2], 1); ltok[i2][p2] = token; lw[i2][p2] = w2;
  __syncthreads();
  if (tid < 8) lbase[tid] = atomicAdd(&counts[tid], lcnt[tid]);
  if (tid == 0){
    lpre[0] = 0;
    #pragma unroll
    for (int e = 0; e < 8; ++e) lpre[e+1] = lpre[e] + lcnt[e];
  }
  __syncthreads();
  tpos[(size_t)token * 2]     = (i1 << 16) + lbase[i1] + p1;
  tpos[(size_t)token * 2 + 1] = (i2 << 16) + lbase[i2] + p2;
  const int total = lpre[8];
  for (int idx = tid; idx < total; idx += 256){
    int e = 0;
    #pragma unroll
    for (int q = 0; q < 7; ++q) e += (idx >= lpre[q + 1]) ? 1 : 0;
    const int i = idx - lpre[e];
    const int dst = (e << 16) + lbase[e] + i;
    pair_tok[dst] = ltok[e][i];
    pair_w[dst]   = lw[e][i];
  }
}

// ---------------------------------------------------------------------------
// Scan: chunk offsets (128-token chunks) + exact token prefix offsets.
// ---------------------------------------------------------------------------
__global__ void scan_kernel(const int* __restrict__ counts, int* __restrict__ offs,
                            int* __restrict__ toffs){
  if (threadIdx.x == 0){
    int o = 0, t = 0;
    #pragma unroll
    for (int e = 0; e < 8; ++e){
      offs[e] = o; o += (counts[e] + 127) >> 7;
      toffs[e] = t; t += counts[e];
    }
    offs[8] = o; toffs[8] = t;
  }
}

// ---------------------------------------------------------------------------
// eg1: h[seq][1024] = gelu(gather(x) @ we1 + be1), bf16.
// 32KB LDS, 4 blocks/CU, XCD-chunked swizzle, swapped MFMA operands.
// ---------------------------------------------------------------------------
__global__ __launch_bounds__(256, 4)
void eg1_kernel(const unsigned short* __restrict__ xbf,
                const unsigned short* __restrict__ we1T,   // [E][1024][512]
                const float* __restrict__ be1,
                const int* __restrict__ counts, const int* __restrict__ offs,
                const int* __restrict__ toffs, const int* __restrict__ pair_tok,
                unsigned short* __restrict__ h){
  const int g = (blockIdx.x & 7) * 1032 + (blockIdx.x >> 3);
  const int chunk = g >> 3, nt = g & 7;
  if (chunk >= offs[8]) return;
  int e = 0;
  #pragma unroll
  for (int q = 0; q < 7; ++q) e += (chunk >= offs[q+1]) ? 1 : 0;
  const int cnt = counts[e];
  const int base = (chunk - offs[e]) << 7;
  const int n0 = nt << 7;
  const int tid = threadIdx.x;
  const int lane = tid & 63;
  const int wv = tid >> 6;
  const int wr = wv >> 1, wc = wv & 1;
  const int lrow = lane & 15, kgrp = lane >> 4;

  __shared__ char lds[32768];
  char* const As = lds;
  char* const Bs = lds + 16384;

  const int srow = tid >> 3;
  const int sdelta = ((tid & 7) << 4) ^ ((srow & 7) << 4);
  unsigned aoff[4];
  #pragma unroll
  for (int i = 0; i < 4; ++i){
    int rr = base + srow + (i << 5);
    int tok = (rr < cnt) ? pair_tok[(e << 16) + rr] : 0;
    aoff[i] = ((unsigned)tok) << 10;
  }
  const char* const xb  = (const char*)xbf;
  const char* const w1b = (const char*)we1T + ((size_t)e << 20);

  f32x4 acc[4][4];                       // [hcol-frag][token-frag]
  #pragma unroll
  for (int i = 0; i < 4; ++i)
    #pragma unroll
    for (int j = 0; j < 4; ++j) acc[i][j] = (f32x4)0.f;

  const int sw = (lrow & 7) << 4;
  for (int kb = 0; kb < 8; ++kb){
    #pragma unroll
    for (int i = 0; i < 4; ++i)
      gload16(xb + aoff[i] + (kb << 7) + sdelta, As + (tid << 4) + (i << 12));
    #pragma unroll
    for (int i = 0; i < 4; ++i)
      gload16(w1b + (size_t)(n0 + srow + (i << 5)) * 1024 + (kb << 7) + sdelta,
              Bs + (tid << 4) + (i << 12));
    __syncthreads();
    #pragma unroll
    for (int s = 0; s < 2; ++s){
      const int kbyte = ((s << 6) + (kgrp << 4)) ^ sw;
      bf16x8 af[4], bf[4];
      #pragma unroll
      for (int f = 0; f < 4; ++f){
        af[f] = *(const bf16x8*)(As + ((wr << 6) + (f << 4) + lrow) * 128 + kbyte);
        bf[f] = *(const bf16x8*)(Bs + ((wc << 6) + (f << 4) + lrow) * 128 + kbyte);
      }
      #pragma unroll
      for (int fb = 0; fb < 4; ++fb)
        #pragma unroll
        for (int fa = 0; fa < 4; ++fa)
          acc[fb][fa] = __builtin_amdgcn_mfma_f32_16x16x32_bf16(bf[fb], af[fa], acc[fb][fa], 0, 0, 0);
    }
    __syncthreads();
  }

  const int hrow0 = toffs[e] + base;
  float4 bias4[4];
  #pragma unroll
  for (int fb = 0; fb < 4; ++fb)
    bias4[fb] = *(const float4*)(be1 + (e << 10) + n0 + (wc << 6) + (fb << 4) + (kgrp << 2));
  #pragma unroll
  for (int fa = 0; fa < 4; ++fa){
    const int tl = (wr << 6) + (fa << 4) + lrow;
    if (base + tl < cnt){
      unsigned short* hp = h + (size_t)(hrow0 + tl) * 1024 + n0 + (wc << 6) + (kgrp << 2);
      #pragma unroll
      for (int fb = 0; fb < 4; ++fb){
        float v, gl; ushort4 o;
        v = acc[fb][fa][0] + bias4[fb].x; gl = 0.5f*v*(1.f+erff(v*0.70710678118654752f)); o.x = f2bf(gl);
        v = acc[fb][fa][1] + bias4[fb].y; gl = 0.5f*v*(1.f+erff(v*0.70710678118654752f)); o.y = f2bf(gl);
        v = acc[fb][fa][2] + bias4[fb].z; gl = 0.5f*v*(1.f+erff(v*0.70710678118654752f)); o.z = f2bf(gl);
        v = acc[fb][fa][3] + bias4[fb].w; gl = 0.5f*v*(1.f+erff(v*0.70710678118654752f)); o.w = f2bf(gl);
        *(ushort4*)(hp + (fb << 4)) = o;
      }
    }
  }
}

// ---------------------------------------------------------------------------
// eg2 (swapped operands): y = h @ we2 + be2 -> ybuf (bf16, no atomics).
// Fallback: atomic accumulate into out.
// ---------------------------------------------------------------------------
__global__ __launch_bounds__(256, 4)
void eg2_kernel(const unsigned short* __restrict__ h,
                const unsigned short* __restrict__ we2T,   // [E][512][1024]
                const float* __restrict__ be2,
                const int* __restrict__ counts, const int* __restrict__ offs,
                const int* __restrict__ toffs, const int* __restrict__ pair_tok,
                const float* __restrict__ pair_w,
                unsigned short* __restrict__ ybuf,         // may be null
                float* __restrict__ out){
  const int g = (blockIdx.x & 7) * 516 + (blockIdx.x >> 3);
  const int chunk = g >> 2, nt = g & 3;
  if (chunk >= offs[8]) return;
  int e = 0;
  #pragma unroll
  for (int q = 0; q < 7; ++q) e += (chunk >= offs[q+1]) ? 1 : 0;
  const int cnt = counts[e];
  const int base = (chunk - offs[e]) << 7;
  const int n0 = nt << 7;
  const int tid = threadIdx.x;
  const int lane = tid & 63;
  const int wv = tid >> 6;
  const int wr = wv >> 1, wc = wv & 1;
  const int lrow = lane & 15, kgrp = lane >> 4;

  __shared__ char lds[32768];
  char* const As = lds;
  char* const Bs = lds + 16384;

  const int srow = tid >> 3;
  const int sdelta = ((tid & 7) << 4) ^ ((srow & 7) << 4);
  const char* const hb  = (const char*)h + (size_t)(toffs[e] + base) * 2048;
  const char* const w2b = (const char*)we2T + ((size_t)e << 20);

  f32x4 acc[4][4];                       // [outcol-frag][token-frag]
  #pragma unroll
  for (int i = 0; i < 4; ++i)
    #pragma unroll
    for (int j = 0; j < 4; ++j) acc[i][j] = (f32x4)0.f;

  const int sw = (lrow & 7) << 4;
  for (int kb = 0; kb < 16; ++kb){
    #pragma unroll
    for (int i = 0; i < 4; ++i)
      gload16(hb + (size_t)(srow + (i << 5)) * 2048 + (kb << 7) + sdelta,
              As + (tid << 4) + (i << 12));
    #pragma unroll
    for (int i = 0; i < 4; ++i)
      gload16(w2b + (size_t)(n0 + srow + (i << 5)) * 2048 + (kb << 7) + sdelta,
              Bs + (tid << 4) + (i << 12));
    __syncthreads();
    #pragma unroll
    for (int s = 0; s < 2; ++s){
      const int kbyte = ((s << 6) + (kgrp << 4)) ^ sw;
      bf16x8 af[4], bf[4];
      #pragma unroll
      for (int f = 0; f < 4; ++f){
        af[f] = *(const bf16x8*)(As + ((wr << 6) + (f << 4) + lrow) * 128 + kbyte);
        bf[f] = *(const bf16x8*)(Bs + ((wc << 6) + (f << 4) + lrow) * 128 + kbyte);
      }
      #pragma unroll
      for (int fb = 0; fb < 4; ++fb)
        #pragma unroll
        for (int fa = 0; fa < 4; ++fa)
          acc[fb][fa] = __builtin_amdgcn_mfma_f32_16x16x32_bf16(bf[fb], af[fa], acc[fb][fa], 0, 0, 0);
    }
    __syncthreads();
  }

  float4 bias4[4];
  #pragma unroll
  for (int fb = 0; fb < 4; ++fb)
    bias4[fb] = *(const float4*)(be2 + (e << 9) + n0 + (wc << 6) + (fb << 4) + (kgrp << 2));

  if (ybuf){
    const int yrow0 = toffs[e] + base;
    #pragma unroll
    for (int fa = 0; fa < 4; ++fa){
      const int tl = (wr << 6) + (fa << 4) + lrow;
      if (base + tl < cnt){
        unsigned short* yp = ybuf + (size_t)(yrow0 + tl) * 512 + n0 + (wc << 6) + (kgrp << 2);
        #pragma unroll
        for (int fb = 0; fb < 4; ++fb){
          ushort4 o;
          o.x = f2bf(acc[fb][fa][0] + bias4[fb].x);
          o.y = f2bf(acc[fb][fa][1] + bias4[fb].y);
          o.z = f2bf(acc[fb][fa][2] + bias4[fb].z);
          o.w = f2bf(acc[fb][fa][3] + bias4[fb].w);
          *(ushort4*)(yp + (fb << 4)) = o;
        }
      }
    }
  } else {
    #pragma unroll
    for (int fa = 0; fa < 4; ++fa){
      const int tl = (wr << 6) + (fa << 4) + lrow;
      const int r = base + tl;
      if (r < cnt){
        const int tok = pair_tok[(e << 16) + r];
        const float wgt = pair_w[(e << 16) + r];
        float* const orow = out + (size_t)tok * 512 + n0 + (wc << 6) + (kgrp << 2);
        #pragma unroll
        for (int fb = 0; fb < 4; ++fb){
          atomicAdd(orow + (fb << 4) + 0, wgt * (acc[fb][fa][0] + bias4[fb].x));
          atomicAdd(orow + (fb << 4) + 1, wgt * (acc[fb][fa][1] + bias4[fb].y));
          atomicAdd(orow + (fb << 4) + 2, wgt * (acc[fb][fa][2] + bias4[fb].z));
          atomicAdd(orow + (fb << 4) + 3, wgt * (acc[fb][fa][3] + bias4[fb].w));
        }
      }
    }
  }
}

// ---------------------------------------------------------------------------
// Combine: out[t] = w0 * y[seq0] + w1 * y[seq1].
// ---------------------------------------------------------------------------
__global__ __launch_bounds__(256, 8)
void combine_kernel(const unsigned short* __restrict__ ybuf,
                    const int* __restrict__ tpos, const int* __restrict__ toffs,
                    const float* __restrict__ pair_w,
                    float* __restrict__ out){
  const int wg = threadIdx.x >> 6;
  const int lane = threadIdx.x & 63;
  for (int t = (blockIdx.x << 2) + wg; t < 65536; t += 4096 * 4){
    const int d0 = tpos[(size_t)t * 2];
    const int d1 = tpos[(size_t)t * 2 + 1];
    const int seq0 = toffs[d0 >> 16] + (d0 & 0xFFFF);
    const int seq1 = toffs[d1 >> 16] + (d1 & 0xFFFF);
    const float w0 = pair_w[d0];
    const float w1 = pair_w[d1];
    const bf16x8 a = *(const bf16x8*)(ybuf + (size_t)seq0 * 512 + (lane << 3));
    const bf16x8 b = *(const bf16x8*)(ybuf + (size_t)seq1 * 512 + (lane << 3));
    float4 o0, o1;
    o0.x = w0*bf2f((unsigned short)a[0]) + w1*bf2f((unsigned short)b[0]);
    o0.y = w0*bf2f((unsigned short)a[1]) + w1*bf2f((unsigned short)b[1]);
    o0.z = w0*bf2f((unsigned short)a[2]) + w1*bf2f((unsigned short)b[2]);
    o0.w = w0*bf2f((unsigned short)a[3]) + w1*bf2f((unsigned short)b[3]);
    o1.x = w0*bf2f((unsigned short)a[4]) + w1*bf2f((unsigned short)b[4]);
    o1.y = w0*bf2f((unsigned short)a[5]) + w1*bf2f((unsigned short)b[5]);
    o1.z = w0*bf2f((unsigned short)a[6]) + w1*bf2f((unsigned short)b[6]);
    o1.w = w0*bf2f((unsigned short)a[7]) + w1*bf2f((unsigned short)b[7]);
    float* op = out + (size_t)t * 512 + (lane << 3);
    *(float4*)op = o0;
    *(float4*)(op + 4) = o1;
  }
}

// ---------------------------------------------------------------------------
extern "C" void kernel_launch(void* const* d_in, const int* in_sizes, int n_in,
                              void* d_out, int out_size, void* d_ws, size_t ws_size,
                              hipStream_t stream){
  const float* x   = (const float*)d_in[0];
  const float* gw1 = (const float*)d_in[1];
  const float* gb1 = (const float*)d_in[2];
  const float* gw2 = (const float*)d_in[3];
  const float* gb2 = (const float*)d_in[4];
  const float* we1 = (const float*)d_in[5];
  const float* be1 = (const float*)d_in[6];
  const float* we2 = (const float*)d_in[7];
  const float* be2 = (const float*)d_in[8];
  float* out = (float*)d_out;

  char* ws = (char*)d_ws;
  const size_t MiB = 1024 * 1024;
  unsigned short* we1T = (unsigned short*)(ws);                 // 8 MiB
  unsigned short* we2T = (unsigned short*)(ws + 8 * MiB);       // 8 MiB
  int*   pair_tok = (int*)  (ws + 16 * MiB);                    // 2 MiB
  float* pair_w   = (float*)(ws + 18 * MiB);                    // 2 MiB
  int*   counts   = (int*)  (ws + 20 * MiB);                    // 64 B
  int*   offs     = (int*)  (ws + 20 * MiB + 256);              // 64 B
  int*   toffs    = (int*)  (ws + 20 * MiB + 512);              // 64 B
  int*   tpos     = (int*)  (ws + 20 * MiB + 4096);             // 512 KiB
  unsigned short* xbf  = (unsigned short*)(ws + 21 * MiB);      // 64 MiB
  float* ghuf          = (float*)(ws + 85 * MiB);               // 64 MiB (gate h)
  unsigned short* hexp = (unsigned short*)(ws + 85 * MiB);      // 256 MiB, aliases ghuf
  unsigned short* ybuf = (unsigned short*)(ws + 341 * MiB);     // 128 MiB
  const bool have_y = ws_size >= 470 * MiB;

  if (!have_y)
    hipMemsetAsync(d_out, 0, (size_t)out_size * sizeof(float), stream);
  hipMemsetAsync(counts, 0, 256, stream);

  hipLaunchKernelGGL(transpose_cvt_kernel, dim3(1024), dim3(256), 0, stream,
                     we1, we1T, 512, 1024);
  hipLaunchKernelGGL(transpose_cvt_kernel, dim3(1024), dim3(256), 0, stream,
                     we2, we2T, 1024, 512);
  hipLaunchKernelGGL(gate_gemm1_kernel, dim3(1024), dim3(256), 0, stream,
                     x, gw1, gb1, ghuf, xbf);
  hipLaunchKernelGGL(gate2_kernel, dim3(256), dim3(256), 0, stream,
                     ghuf, gw2, gb2, counts, pair_tok, pair_w, tpos);
  hipLaunchKernelGGL(scan_kernel, dim3(1), dim3(64), 0, stream, counts, offs, toffs);

  hipLaunchKernelGGL(eg1_kernel, dim3(8256), dim3(256), 0, stream,
                     xbf, we1T, be1, counts, offs, toffs, pair_tok, hexp);
  hipLaunchKernelGGL(eg2_kernel, dim3(4128), dim3(256), 0, stream,
                     hexp, we2T, be2, counts, offs, toffs, pair_tok, pair_w,
                     have_y ? ybuf : (unsigned short*)nullptr, out);
  if (have_y)
    hipLaunchKernelGGL(combine_kernel, dim3(4096), dim3(256), 0, stream,
                       ybuf, tpos, toffs, pair_w, out);
}

// Round 13
// 685.113 us; speedup vs baseline: 1.3064x; 1.0172x over previous
//
#include <hip/hip_runtime.h>
#include <hip/hip_bf16.h>
#include <math.h>

// MoE: T=65536 tokens, D=512, H=1024, E=8, TOP_K=2.
// R13: R12's BK=32 pipeline had a provable swizzle bug (3-bit key on 64B
// rows -> cross-row reads; also 4-way-conflict geometry). Reverted eg1/eg2
// to R11's verified BK=64 loop. Kept ONLY the tanh-gelu (9 ops vs ~30 for
// erff; deviation 5e-4 << bf16 rounding of h).

typedef __attribute__((ext_vector_type(8))) short bf16x8;
typedef __attribute__((ext_vector_type(4))) float f32x4;

__device__ __forceinline__ unsigned short f2bf(float f){
  unsigned u = __builtin_bit_cast(unsigned, f);
  u += 0x7FFFu + ((u >> 16) & 1u);          // RNE
  return (unsigned short)(u >> 16);
}

__device__ __forceinline__ float bf2f(unsigned short u){
  return __builtin_bit_cast(float, (unsigned)u << 16);
}

__device__ __forceinline__ float gelu_fast(float v){
  // 0.5v(1+tanh(sqrt(2/pi)(v+0.044715v^3))) = v * sigmoid(1.59576909*(v+0.044715v^3))
  float z = 1.59576909f * v * fmaf(0.044715f, v * v, 1.f);
  return v / (1.f + __expf(-z));
}

__device__ __forceinline__ void gload16(const void* g, void* l){
  __builtin_amdgcn_global_load_lds((const __attribute__((address_space(1))) unsigned int*)g,
                                   (__attribute__((address_space(3))) unsigned int*)l, 16, 0, 0);
}

// ---------------------------------------------------------------------------
// Transpose + fp32->bf16 convert:  in [E][R][C] f32  ->  out [E][C][R] bf16
// ---------------------------------------------------------------------------
__global__ __launch_bounds__(256, 4)
void transpose_cvt_kernel(const float* __restrict__ in, unsigned short* __restrict__ out,
                          int R, int C){
  const int tilesR = R >> 6, tilesC = C >> 6;
  const int b = blockIdx.x;
  const int e = b / (tilesR * tilesC);
  const int rem = b % (tilesR * tilesC);
  const int rb = (rem / tilesC) << 6;
  const int cb = (rem % tilesC) << 6;
  const float* src = in + (size_t)e * R * C;
  unsigned short* dst = out + (size_t)e * R * C;
  __shared__ float t[64][65];
  const int r0 = threadIdx.x >> 4;
  const int c4 = (threadIdx.x & 15) << 2;
  #pragma unroll
  for (int p = 0; p < 4; ++p){
    int r = r0 + (p << 4);
    const float4 v = *(const float4*)(src + (size_t)(rb + r) * C + cb + c4);
    t[r][c4+0] = v.x; t[r][c4+1] = v.y; t[r][c4+2] = v.z; t[r][c4+3] = v.w;
  }
  __syncthreads();
  #pragma unroll
  for (int p = 0; p < 4; ++p){
    int cr = r0 + (p << 4);
    ushort4 o;
    o.x = f2bf(t[c4+0][cr]); o.y = f2bf(t[c4+1][cr]);
    o.z = f2bf(t[c4+2][cr]); o.w = f2bf(t[c4+3][cr]);
    *(ushort4*)(dst + (size_t)(cb + cr) * R + rb + c4) = o;
  }
}

// ---------------------------------------------------------------------------
// Gate GEMM1 (fp32) + fused x->bf16: h = relu(x @ gw1 + gb1); xbf = bf16(x).
// Thread tile 16 tok x 4 col (R11).
// ---------------------------------------------------------------------------
__global__ __launch_bounds__(256, 3)
void gate_gemm1_kernel(const float* __restrict__ x, const float* __restrict__ gw1,
                       const float* __restrict__ gb1, float* __restrict__ h,
                       unsigned short* __restrict__ xbf){
  __shared__ float xs[32][68];          // [k][tok]
  __shared__ float g1s[32][256];        // [k][col]
  const int tid = threadIdx.x;
  const int t0 = blockIdx.x << 6;
  const int tg = tid >> 6;              // wave id: tokens tg*16..+15
  const int cg = tid & 63;              // cols 4cg..4cg+3

  const int xtok = tid >> 2, xk8 = (tid & 3) << 3;

  float acc[16][4];
  #pragma unroll
  for (int t = 0; t < 16; ++t)
    #pragma unroll
    for (int c = 0; c < 4; ++c) acc[t][c] = 0.f;

  for (int kb = 0; kb < 512; kb += 32){
    __syncthreads();
    {
      const float4 v0 = *(const float4*)(x + (size_t)(t0 + xtok) * 512 + kb + xk8);
      const float4 v1 = *(const float4*)(x + (size_t)(t0 + xtok) * 512 + kb + xk8 + 4);
      xs[xk8+0][xtok] = v0.x; xs[xk8+1][xtok] = v0.y;
      xs[xk8+2][xtok] = v0.z; xs[xk8+3][xtok] = v0.w;
      xs[xk8+4][xtok] = v1.x; xs[xk8+5][xtok] = v1.y;
      xs[xk8+6][xtok] = v1.z; xs[xk8+7][xtok] = v1.w;
      ushort4 o0, o1;
      o0.x = f2bf(v0.x); o0.y = f2bf(v0.y); o0.z = f2bf(v0.z); o0.w = f2bf(v0.w);
      o1.x = f2bf(v1.x); o1.y = f2bf(v1.y); o1.z = f2bf(v1.z); o1.w = f2bf(v1.w);
      *(ushort4*)(xbf + (size_t)(t0 + xtok) * 512 + kb + xk8)     = o0;
      *(ushort4*)(xbf + (size_t)(t0 + xtok) * 512 + kb + xk8 + 4) = o1;
    }
    #pragma unroll
    for (int p = 0; p < 8; ++p){
      int f = tid + (p << 8);
      int r = f >> 6, c4 = (f & 63) << 2;
      *(float4*)&g1s[r][c4] = *(const float4*)(gw1 + (size_t)(kb + r) * 256 + c4);
    }
    __syncthreads();
    #pragma unroll 4
    for (int k = 0; k < 32; ++k){
      const float4 wv = *(const float4*)&g1s[k][cg << 2];
      const float4 xq0 = *(const float4*)&xs[k][(tg << 4) + 0];
      const float4 xq1 = *(const float4*)&xs[k][(tg << 4) + 4];
      const float4 xq2 = *(const float4*)&xs[k][(tg << 4) + 8];
      const float4 xq3 = *(const float4*)&xs[k][(tg << 4) + 12];
      #define FMA4(T, XV) \
        acc[T][0] = fmaf(XV, wv.x, acc[T][0]); acc[T][1] = fmaf(XV, wv.y, acc[T][1]); \
        acc[T][2] = fmaf(XV, wv.z, acc[T][2]); acc[T][3] = fmaf(XV, wv.w, acc[T][3]);
      FMA4(0,  xq0.x) FMA4(1,  xq0.y) FMA4(2,  xq0.z) FMA4(3,  xq0.w)
      FMA4(4,  xq1.x) FMA4(5,  xq1.y) FMA4(6,  xq1.z) FMA4(7,  xq1.w)
      FMA4(8,  xq2.x) FMA4(9,  xq2.y) FMA4(10, xq2.z) FMA4(11, xq2.w)
      FMA4(12, xq3.x) FMA4(13, xq3.y) FMA4(14, xq3.z) FMA4(15, xq3.w)
      #undef FMA4
    }
  }

  const float4 bias = *(const float4*)(gb1 + (cg << 2));
  float* hp = h + (size_t)(t0 + (tg << 4)) * 256 + (cg << 2);
  #pragma unroll
  for (int t = 0; t < 16; ++t){
    float4 o;
    o.x = fmaxf(acc[t][0] + bias.x, 0.f);
    o.y = fmaxf(acc[t][1] + bias.y, 0.f);
    o.z = fmaxf(acc[t][2] + bias.z, 0.f);
    o.w = fmaxf(acc[t][3] + bias.w, 0.f);
    *(float4*)(hp + (size_t)t * 256) = o;
  }
}

// ---------------------------------------------------------------------------
// Gate2: logits, softmax, top2, re-softmax, block-aggregated scatter.
// Records tpos[token*2 + {0,1}] = (e<<16)|list_pos for the combiner.
// ---------------------------------------------------------------------------
__global__ __launch_bounds__(256, 2)
void gate2_kernel(const float* __restrict__ h, const float* __restrict__ gw2,
                  const float* __restrict__ gb2,
                  int* __restrict__ counts, int* __restrict__ pair_tok,
                  float* __restrict__ pair_w, int* __restrict__ tpos){
  __shared__ float g2s[256 * 9];
  __shared__ int   lcnt[8];
  __shared__ int   lbase[8];
  __shared__ int   lpre[9];
  __shared__ int   ltok[8][256];
  __shared__ float lw[8][256];
  const int tid = threadIdx.x;
  const int t0 = blockIdx.x << 8;

  #pragma unroll
  for (int p = 0; p < 8; ++p){
    int idx = tid + (p << 8);
    g2s[(idx >> 3) * 9 + (idx & 7)] = gw2[idx];
  }
  if (tid < 8) lcnt[tid] = 0;
  __syncthreads();

  const int token = t0 + tid;
  float pl[8];
  #pragma unroll
  for (int e = 0; e < 8; ++e) pl[e] = gb2[e];
  for (int j = 0; j < 64; ++j){
    const float4 hv = *(const float4*)(h + (size_t)token * 256 + (j << 2));
    #pragma unroll
    for (int i = 0; i < 4; ++i){
      const float hx = ((const float*)&hv)[i];
      #pragma unroll
      for (int e = 0; e < 8; ++e)
        pl[e] = fmaf(hx, g2s[((j << 2) + i) * 9 + e], pl[e]);
    }
  }
  float m = pl[0];
  #pragma unroll
  for (int e = 1; e < 8; ++e) m = fmaxf(m, pl[e]);
  float p[8]; float s = 0.f;
  #pragma unroll
  for (int e = 0; e < 8; ++e){ p[e] = expf(pl[e] - m); s += p[e]; }
  float inv = 1.f / s;
  float m1 = -1.f, m2 = -1.f; int i1 = 0, i2 = 0;
  #pragma unroll
  for (int e = 0; e < 8; ++e){
    float pe = p[e] * inv;
    if (pe > m1){ m2 = m1; i2 = i1; m1 = pe; i1 = e; }
    else if (pe > m2){ m2 = pe; i2 = e; }
  }
  float e21 = expf(m2 - m1);
  float w1 = 1.f / (1.f + e21);
  float w2 = 1.f - w1;
  int p1 = atomicAdd(&lcnt[i1], 1); ltok[i1][p1] = token; lw[i1][p1] = w1;
  int p2 = atomicAdd(&lcnt[i2], 1); ltok[i2][p2] = token; lw[i2][p2] = w2;
  __syncthreads();
  if (tid < 8) lbase[tid] = atomicAdd(&counts[tid], lcnt[tid]);
  if (tid == 0){
    lpre[0] = 0;
    #pragma unroll
    for (int e = 0; e < 8; ++e) lpre[e+1] = lpre[e] + lcnt[e];
  }
  __syncthreads();
  tpos[(size_t)token * 2]     = (i1 << 16) + lbase[i1] + p1;
  tpos[(size_t)token * 2 + 1] = (i2 << 16) + lbase[i2] + p2;
  const int total = lpre[8];
  for (int idx = tid; idx < total; idx += 256){
    int e = 0;
    #pragma unroll
    for (int q = 0; q < 7; ++q) e += (idx >= lpre[q + 1]) ? 1 : 0;
    const int i = idx - lpre[e];
    const int dst = (e << 16) + lbase[e] + i;
    pair_tok[dst] = ltok[e][i];
    pair_w[dst]   = lw[e][i];
  }
}

// ---------------------------------------------------------------------------
// Scan: chunk offsets (128-token chunks) + exact token prefix offsets.
// ---------------------------------------------------------------------------
__global__ void scan_kernel(const int* __restrict__ counts, int* __restrict__ offs,
                            int* __restrict__ toffs){
  if (threadIdx.x == 0){
    int o = 0, t = 0;
    #pragma unroll
    for (int e = 0; e < 8; ++e){
      offs[e] = o; o += (counts[e] + 127) >> 7;
      toffs[e] = t; t += counts[e];
    }
    offs[8] = o; toffs[8] = t;
  }
}

// ---------------------------------------------------------------------------
// eg1 (R11-verified loop): h[seq][1024] = gelu(gather(x) @ we1 + be1), bf16.
// 32KB LDS, 4 blocks/CU, XCD-chunked swizzle, swapped MFMA operands,
// tanh-gelu epilogue.
// ---------------------------------------------------------------------------
__global__ __launch_bounds__(256, 4)
void eg1_kernel(const unsigned short* __restrict__ xbf,
                const unsigned short* __restrict__ we1T,   // [E][1024][512]
                const float* __restrict__ be1,
                const int* __restrict__ counts, const int* __restrict__ offs,
                const int* __restrict__ toffs, const int* __restrict__ pair_tok,
                unsigned short* __restrict__ h){
  const int g = (blockIdx.x & 7) * 1032 + (blockIdx.x >> 3);
  const int chunk = g >> 3, nt = g & 7;
  if (chunk >= offs[8]) return;
  int e = 0;
  #pragma unroll
  for (int q = 0; q < 7; ++q) e += (chunk >= offs[q+1]) ? 1 : 0;
  const int cnt = counts[e];
  const int base = (chunk - offs[e]) << 7;
  const int n0 = nt << 7;
  const int tid = threadIdx.x;
  const int lane = tid & 63;
  const int wv = tid >> 6;
  const int wr = wv >> 1, wc = wv & 1;
  const int lrow = lane & 15, kgrp = lane >> 4;

  __shared__ char lds[32768];
  char* const As = lds;
  char* const Bs = lds + 16384;

  const int srow = tid >> 3;
  const int sdelta = ((tid & 7) << 4) ^ ((srow & 7) << 4);
  unsigned aoff[4];
  #pragma unroll
  for (int i = 0; i < 4; ++i){
    int rr = base + srow + (i << 5);
    int tok = (rr < cnt) ? pair_tok[(e << 16) + rr] : 0;
    aoff[i] = ((unsigned)tok) << 10;
  }
  const char* const xb  = (const char*)xbf;
  const char* const w1b = (const char*)we1T + ((size_t)e << 20);

  f32x4 acc[4][4];                       // [hcol-frag][token-frag]
  #pragma unroll
  for (int i = 0; i < 4; ++i)
    #pragma unroll
    for (int j = 0; j < 4; ++j) acc[i][j] = (f32x4)0.f;

  const int sw = (lrow & 7) << 4;
  for (int kb = 0; kb < 8; ++kb){
    #pragma unroll
    for (int i = 0; i < 4; ++i)
      gload16(xb + aoff[i] + (kb << 7) + sdelta, As + (tid << 4) + (i << 12));
    #pragma unroll
    for (int i = 0; i < 4; ++i)
      gload16(w1b + (size_t)(n0 + srow + (i << 5)) * 1024 + (kb << 7) + sdelta,
              Bs + (tid << 4) + (i << 12));
    __syncthreads();
    #pragma unroll
    for (int s = 0; s < 2; ++s){
      const int kbyte = ((s << 6) + (kgrp << 4)) ^ sw;
      bf16x8 af[4], bf[4];
      #pragma unroll
      for (int f = 0; f < 4; ++f){
        af[f] = *(const bf16x8*)(As + ((wr << 6) + (f << 4) + lrow) * 128 + kbyte);
        bf[f] = *(const bf16x8*)(Bs + ((wc << 6) + (f << 4) + lrow) * 128 + kbyte);
      }
      #pragma unroll
      for (int fb = 0; fb < 4; ++fb)
        #pragma unroll
        for (int fa = 0; fa < 4; ++fa)
          acc[fb][fa] = __builtin_amdgcn_mfma_f32_16x16x32_bf16(bf[fb], af[fa], acc[fb][fa], 0, 0, 0);
    }
    __syncthreads();
  }

  const int hrow0 = toffs[e] + base;
  float4 bias4[4];
  #pragma unroll
  for (int fb = 0; fb < 4; ++fb)
    bias4[fb] = *(const float4*)(be1 + (e << 10) + n0 + (wc << 6) + (fb << 4) + (kgrp << 2));
  #pragma unroll
  for (int fa = 0; fa < 4; ++fa){
    const int tl = (wr << 6) + (fa << 4) + lrow;
    if (base + tl < cnt){
      unsigned short* hp = h + (size_t)(hrow0 + tl) * 1024 + n0 + (wc << 6) + (kgrp << 2);
      #pragma unroll
      for (int fb = 0; fb < 4; ++fb){
        ushort4 o;
        o.x = f2bf(gelu_fast(acc[fb][fa][0] + bias4[fb].x));
        o.y = f2bf(gelu_fast(acc[fb][fa][1] + bias4[fb].y));
        o.z = f2bf(gelu_fast(acc[fb][fa][2] + bias4[fb].z));
        o.w = f2bf(gelu_fast(acc[fb][fa][3] + bias4[fb].w));
        *(ushort4*)(hp + (fb << 4)) = o;
      }
    }
  }
}

// ---------------------------------------------------------------------------
// eg2 (R11-verified loop, swapped operands): y = h @ we2 + be2 -> ybuf.
// Fallback: atomic accumulate into out.
// ---------------------------------------------------------------------------
__global__ __launch_bounds__(256, 4)
void eg2_kernel(const unsigned short* __restrict__ h,
                const unsigned short* __restrict__ we2T,   // [E][512][1024]
                const float* __restrict__ be2,
                const int* __restrict__ counts, const int* __restrict__ offs,
                const int* __restrict__ toffs, const int* __restrict__ pair_tok,
                const float* __restrict__ pair_w,
                unsigned short* __restrict__ ybuf,         // may be null
                float* __restrict__ out){
  const int g = (blockIdx.x & 7) * 516 + (blockIdx.x >> 3);
  const int chunk = g >> 2, nt = g & 3;
  if (chunk >= offs[8]) return;
  int e = 0;
  #pragma unroll
  for (int q = 0; q < 7; ++q) e += (chunk >= offs[q+1]) ? 1 : 0;
  const int cnt = counts[e];
  const int base = (chunk - offs[e]) << 7;
  const int n0 = nt << 7;
  const int tid = threadIdx.x;
  const int lane = tid & 63;
  const int wv = tid >> 6;
  const int wr = wv >> 1, wc = wv & 1;
  const int lrow = lane & 15, kgrp = lane >> 4;

  __shared__ char lds[32768];
  char* const As = lds;
  char* const Bs = lds + 16384;

  const int srow = tid >> 3;
  const int sdelta = ((tid & 7) << 4) ^ ((srow & 7) << 4);
  const char* const hb  = (const char*)h + (size_t)(toffs[e] + base) * 2048;
  const char* const w2b = (const char*)we2T + ((size_t)e << 20);

  f32x4 acc[4][4];                       // [outcol-frag][token-frag]
  #pragma unroll
  for (int i = 0; i < 4; ++i)
    #pragma unroll
    for (int j = 0; j < 4; ++j) acc[i][j] = (f32x4)0.f;

  const int sw = (lrow & 7) << 4;
  for (int kb = 0; kb < 16; ++kb){
    #pragma unroll
    for (int i = 0; i < 4; ++i)
      gload16(hb + (size_t)(srow + (i << 5)) * 2048 + (kb << 7) + sdelta,
              As + (tid << 4) + (i << 12));
    #pragma unroll
    for (int i = 0; i < 4; ++i)
      gload16(w2b + (size_t)(n0 + srow + (i << 5)) * 2048 + (kb << 7) + sdelta,
              Bs + (tid << 4) + (i << 12));
    __syncthreads();
    #pragma unroll
    for (int s = 0; s < 2; ++s){
      const int kbyte = ((s << 6) + (kgrp << 4)) ^ sw;
      bf16x8 af[4], bf[4];
      #pragma unroll
      for (int f = 0; f < 4; ++f){
        af[f] = *(const bf16x8*)(As + ((wr << 6) + (f << 4) + lrow) * 128 + kbyte);
        bf[f] = *(const bf16x8*)(Bs + ((wc << 6) + (f << 4) + lrow) * 128 + kbyte);
      }
      #pragma unroll
      for (int fb = 0; fb < 4; ++fb)
        #pragma unroll
        for (int fa = 0; fa < 4; ++fa)
          acc[fb][fa] = __builtin_amdgcn_mfma_f32_16x16x32_bf16(bf[fb], af[fa], acc[fb][fa], 0, 0, 0);
    }
    __syncthreads();
  }

  float4 bias4[4];
  #pragma unroll
  for (int fb = 0; fb < 4; ++fb)
    bias4[fb] = *(const float4*)(be2 + (e << 9) + n0 + (wc << 6) + (fb << 4) + (kgrp << 2));

  if (ybuf){
    const int yrow0 = toffs[e] + base;
    #pragma unroll
    for (int fa = 0; fa < 4; ++fa){
      const int tl = (wr << 6) + (fa << 4) + lrow;
      if (base + tl < cnt){
        unsigned short* yp = ybuf + (size_t)(yrow0 + tl) * 512 + n0 + (wc << 6) + (kgrp << 2);
        #pragma unroll
        for (int fb = 0; fb < 4; ++fb){
          ushort4 o;
          o.x = f2bf(acc[fb][fa][0] + bias4[fb].x);
          o.y = f2bf(acc[fb][fa][1] + bias4[fb].y);
          o.z = f2bf(acc[fb][fa][2] + bias4[fb].z);
          o.w = f2bf(acc[fb][fa][3] + bias4[fb].w);
          *(ushort4*)(yp + (fb << 4)) = o;
        }
      }
    }
  } else {
    #pragma unroll
    for (int fa = 0; fa < 4; ++fa){
      const int tl = (wr << 6) + (fa << 4) + lrow;
      const int r = base + tl;
      if (r < cnt){
        const int tok = pair_tok[(e << 16) + r];
        const float wgt = pair_w[(e << 16) + r];
        float* const orow = out + (size_t)tok * 512 + n0 + (wc << 6) + (kgrp << 2);
        #pragma unroll
        for (int fb = 0; fb < 4; ++fb){
          atomicAdd(orow + (fb << 4) + 0, wgt * (acc[fb][fa][0] + bias4[fb].x));
          atomicAdd(orow + (fb << 4) + 1, wgt * (acc[fb][fa][1] + bias4[fb].y));
          atomicAdd(orow + (fb << 4) + 2, wgt * (acc[fb][fa][2] + bias4[fb].z));
          atomicAdd(orow + (fb << 4) + 3, wgt * (acc[fb][fa][3] + bias4[fb].w));
        }
      }
    }
  }
}

// ---------------------------------------------------------------------------
// Combine: out[t] = w0 * y[seq0] + w1 * y[seq1].
// ---------------------------------------------------------------------------
__global__ __launch_bounds__(256, 8)
void combine_kernel(const unsigned short* __restrict__ ybuf,
                    const int* __restrict__ tpos, const int* __restrict__ toffs,
                    const float* __restrict__ pair_w,
                    float* __restrict__ out){
  const int wg = threadIdx.x >> 6;
  const int lane = threadIdx.x & 63;
  for (int t = (blockIdx.x << 2) + wg; t < 65536; t += 4096 * 4){
    const int d0 = tpos[(size_t)t * 2];
    const int d1 = tpos[(size_t)t * 2 + 1];
    const int seq0 = toffs[d0 >> 16] + (d0 & 0xFFFF);
    const int seq1 = toffs[d1 >> 16] + (d1 & 0xFFFF);
    const float w0 = pair_w[d0];
    const float w1 = pair_w[d1];
    const bf16x8 a = *(const bf16x8*)(ybuf + (size_t)seq0 * 512 + (lane << 3));
    const bf16x8 b = *(const bf16x8*)(ybuf + (size_t)seq1 * 512 + (lane << 3));
    float4 o0, o1;
    o0.x = w0*bf2f((unsigned short)a[0]) + w1*bf2f((unsigned short)b[0]);
    o0.y = w0*bf2f((unsigned short)a[1]) + w1*bf2f((unsigned short)b[1]);
    o0.z = w0*bf2f((unsigned short)a[2]) + w1*bf2f((unsigned short)b[2]);
    o0.w = w0*bf2f((unsigned short)a[3]) + w1*bf2f((unsigned short)b[3]);
    o1.x = w0*bf2f((unsigned short)a[4]) + w1*bf2f((unsigned short)b[4]);
    o1.y = w0*bf2f((unsigned short)a[5]) + w1*bf2f((unsigned short)b[5]);
    o1.z = w0*bf2f((unsigned short)a[6]) + w1*bf2f((unsigned short)b[6]);
    o1.w = w0*bf2f((unsigned short)a[7]) + w1*bf2f((unsigned short)b[7]);
    float* op = out + (size_t)t * 512 + (lane << 3);
    *(float4*)op = o0;
    *(float4*)(op + 4) = o1;
  }
}

// ---------------------------------------------------------------------------
extern "C" void kernel_launch(void* const* d_in, const int* in_sizes, int n_in,
                              void* d_out, int out_size, void* d_ws, size_t ws_size,
                              hipStream_t stream){
  const float* x   = (const float*)d_in[0];
  const float* gw1 = (const float*)d_in[1];
  const float* gb1 = (const float*)d_in[2];
  const float* gw2 = (const float*)d_in[3];
  const float* gb2 = (const float*)d_in[4];
  const float* we1 = (const float*)d_in[5];
  const float* be1 = (const float*)d_in[6];
  const float* we2 = (const float*)d_in[7];
  const float* be2 = (const float*)d_in[8];
  float* out = (float*)d_out;

  char* ws = (char*)d_ws;
  const size_t MiB = 1024 * 1024;
  unsigned short* we1T = (unsigned short*)(ws);                 // 8 MiB
  unsigned short* we2T = (unsigned short*)(ws + 8 * MiB);       // 8 MiB
  int*   pair_tok = (int*)  (ws + 16 * MiB);                    // 2 MiB
  float* pair_w   = (float*)(ws + 18 * MiB);                    // 2 MiB
  int*   counts   = (int*)  (ws + 20 * MiB);                    // 64 B
  int*   offs     = (int*)  (ws + 20 * MiB + 256);              // 64 B
  int*   toffs    = (int*)  (ws + 20 * MiB + 512);              // 64 B
  int*   tpos     = (int*)  (ws + 20 * MiB + 4096);             // 512 KiB
  unsigned short* xbf  = (unsigned short*)(ws + 21 * MiB);      // 64 MiB
  float* ghuf          = (float*)(ws + 85 * MiB);               // 64 MiB (gate h)
  unsigned short* hexp = (unsigned short*)(ws + 85 * MiB);      // 256 MiB, aliases ghuf
  unsigned short* ybuf = (unsigned short*)(ws + 341 * MiB);     // 128 MiB
  const bool have_y = ws_size >= 470 * MiB;

  if (!have_y)
    hipMemsetAsync(d_out, 0, (size_t)out_size * sizeof(float), stream);
  hipMemsetAsync(counts, 0, 256, stream);

  hipLaunchKernelGGL(transpose_cvt_kernel, dim3(1024), dim3(256), 0, stream,
                     we1, we1T, 512, 1024);
  hipLaunchKernelGGL(transpose_cvt_kernel, dim3(1024), dim3(256), 0, stream,
                     we2, we2T, 1024, 512);
  hipLaunchKernelGGL(gate_gemm1_kernel, dim3(1024), dim3(256), 0, stream,
                     x, gw1, gb1, ghuf, xbf);
  hipLaunchKernelGGL(gate2_kernel, dim3(256), dim3(256), 0, stream,
                     ghuf, gw2, gb2, counts, pair_tok, pair_w, tpos);
  hipLaunchKernelGGL(scan_kernel, dim3(1), dim3(64), 0, stream, counts, offs, toffs);

  hipLaunchKernelGGL(eg1_kernel, dim3(8256), dim3(256), 0, stream,
                     xbf, we1T, be1, counts, offs, toffs, pair_tok, hexp);
  hipLaunchKernelGGL(eg2_kernel, dim3(4128), dim3(256), 0, stream,
                     hexp, we2T, be2, counts, offs, toffs, pair_tok, pair_w,
                     have_y ? ybuf : (unsigned short*)nullptr, out);
  if (have_y)
    hipLaunchKernelGGL(combine_kernel, dim3(4096), dim3(256), 0, stream,
                       ybuf, tpos, toffs, pair_w, out);
}

// Round 14
// 681.279 us; speedup vs baseline: 1.3138x; 1.0056x over previous
//
#include <hip/hip_runtime.h>
#include <hip/hip_bf16.h>
#include <math.h>

// MoE: T=65536 tokens, D=512, H=1024, E=8, TOP_K=2.
// R14: gate_gemm1 gets a register-prefetch pipeline (load slice kb+1 into
// regs right after the write-barrier; 32-k FMA block hides the latency).
// launch_bounds(256) unbounded VGPR (audit: ~130 live; cap-128 would spill).
// Everything else identical to R13 (verified).

typedef __attribute__((ext_vector_type(8))) short bf16x8;
typedef __attribute__((ext_vector_type(4))) float f32x4;

__device__ __forceinline__ unsigned short f2bf(float f){
  unsigned u = __builtin_bit_cast(unsigned, f);
  u += 0x7FFFu + ((u >> 16) & 1u);          // RNE
  return (unsigned short)(u >> 16);
}

__device__ __forceinline__ float bf2f(unsigned short u){
  return __builtin_bit_cast(float, (unsigned)u << 16);
}

__device__ __forceinline__ float gelu_fast(float v){
  // v * sigmoid(1.59576909*(v+0.044715v^3))  (tanh-form gelu)
  float z = 1.59576909f * v * fmaf(0.044715f, v * v, 1.f);
  return v / (1.f + __expf(-z));
}

__device__ __forceinline__ void gload16(const void* g, void* l){
  __builtin_amdgcn_global_load_lds((const __attribute__((address_space(1))) unsigned int*)g,
                                   (__attribute__((address_space(3))) unsigned int*)l, 16, 0, 0);
}

// ---------------------------------------------------------------------------
// Transpose + fp32->bf16 convert:  in [E][R][C] f32  ->  out [E][C][R] bf16
// ---------------------------------------------------------------------------
__global__ __launch_bounds__(256, 4)
void transpose_cvt_kernel(const float* __restrict__ in, unsigned short* __restrict__ out,
                          int R, int C){
  const int tilesR = R >> 6, tilesC = C >> 6;
  const int b = blockIdx.x;
  const int e = b / (tilesR * tilesC);
  const int rem = b % (tilesR * tilesC);
  const int rb = (rem / tilesC) << 6;
  const int cb = (rem % tilesC) << 6;
  const float* src = in + (size_t)e * R * C;
  unsigned short* dst = out + (size_t)e * R * C;
  __shared__ float t[64][65];
  const int r0 = threadIdx.x >> 4;
  const int c4 = (threadIdx.x & 15) << 2;
  #pragma unroll
  for (int p = 0; p < 4; ++p){
    int r = r0 + (p << 4);
    const float4 v = *(const float4*)(src + (size_t)(rb + r) * C + cb + c4);
    t[r][c4+0] = v.x; t[r][c4+1] = v.y; t[r][c4+2] = v.z; t[r][c4+3] = v.w;
  }
  __syncthreads();
  #pragma unroll
  for (int p = 0; p < 4; ++p){
    int cr = r0 + (p << 4);
    ushort4 o;
    o.x = f2bf(t[c4+0][cr]); o.y = f2bf(t[c4+1][cr]);
    o.z = f2bf(t[c4+2][cr]); o.w = f2bf(t[c4+3][cr]);
    *(ushort4*)(dst + (size_t)(cb + cr) * R + rb + c4) = o;
  }
}

// ---------------------------------------------------------------------------
// Gate GEMM1 (fp32) + fused x->bf16: h = relu(x @ gw1 + gb1); xbf = bf16(x).
// Thread tile 16 tok x 4 col. Register-prefetch pipeline:
//   write regs(slice kb)->LDS (+xbf) -> bar -> load regs(slice kb+1) ->
//   32-k FMA (hides loads) -> bar.
// gw1 prefetch mapping: ng[p] = gw1[(kb + tg + 4p)*256 + cg*4] (p<8), which
// stores to g1s[tg+4p][cg*4] -- full-row float4 writes, conflict-free.
// ---------------------------------------------------------------------------
__global__ __launch_bounds__(256)
void gate_gemm1_kernel(const float* __restrict__ x, const float* __restrict__ gw1,
                       const float* __restrict__ gb1, float* __restrict__ h,
                       unsigned short* __restrict__ xbf){
  __shared__ float xs[32][68];          // [k][tok]
  __shared__ float g1s[32][256];        // [k][col]
  const int tid = threadIdx.x;
  const int t0 = blockIdx.x << 6;
  const int tg = tid >> 6;              // wave id: tokens tg*16..+15 / gw1 row base
  const int cg = tid & 63;              // cols 4cg..4cg+3

  const int xtok = tid >> 2, xk8 = (tid & 3) << 3;

  float4 ng0, ng1, ng2, ng3, ng4, ng5, ng6, ng7;
  float4 nx0, nx1;
  { // prologue: load slice 0 into regs
    const float* gp = gw1 + (size_t)tg * 256 + (cg << 2);
    ng0 = *(const float4*)(gp);
    ng1 = *(const float4*)(gp + 4*256);
    ng2 = *(const float4*)(gp + 8*256);
    ng3 = *(const float4*)(gp + 12*256);
    ng4 = *(const float4*)(gp + 16*256);
    ng5 = *(const float4*)(gp + 20*256);
    ng6 = *(const float4*)(gp + 24*256);
    ng7 = *(const float4*)(gp + 28*256);
    nx0 = *(const float4*)(x + (size_t)(t0 + xtok) * 512 + xk8);
    nx1 = *(const float4*)(x + (size_t)(t0 + xtok) * 512 + xk8 + 4);
  }

  float acc[16][4];
  #pragma unroll
  for (int t = 0; t < 16; ++t)
    #pragma unroll
    for (int c = 0; c < 4; ++c) acc[t][c] = 0.f;

  for (int kb = 0; kb < 512; kb += 32){
    { // write staged slice kb to LDS + emit xbf
      xs[xk8+0][xtok] = nx0.x; xs[xk8+1][xtok] = nx0.y;
      xs[xk8+2][xtok] = nx0.z; xs[xk8+3][xtok] = nx0.w;
      xs[xk8+4][xtok] = nx1.x; xs[xk8+5][xtok] = nx1.y;
      xs[xk8+6][xtok] = nx1.z; xs[xk8+7][xtok] = nx1.w;
      ushort4 o0, o1;
      o0.x = f2bf(nx0.x); o0.y = f2bf(nx0.y); o0.z = f2bf(nx0.z); o0.w = f2bf(nx0.w);
      o1.x = f2bf(nx1.x); o1.y = f2bf(nx1.y); o1.z = f2bf(nx1.z); o1.w = f2bf(nx1.w);
      *(ushort4*)(xbf + (size_t)(t0 + xtok) * 512 + kb + xk8)     = o0;
      *(ushort4*)(xbf + (size_t)(t0 + xtok) * 512 + kb + xk8 + 4) = o1;
      float* gq = &g1s[tg][cg << 2];
      *(float4*)(gq)           = ng0;
      *(float4*)(gq + 4*256)   = ng1;
      *(float4*)(gq + 8*256)   = ng2;
      *(float4*)(gq + 12*256)  = ng3;
      *(float4*)(gq + 16*256)  = ng4;
      *(float4*)(gq + 20*256)  = ng5;
      *(float4*)(gq + 24*256)  = ng6;
      *(float4*)(gq + 28*256)  = ng7;
    }
    __syncthreads();
    if (kb < 480){ // issue next slice's loads; FMA block below hides them
      const float* gp = gw1 + (size_t)(kb + 32 + tg) * 256 + (cg << 2);
      ng0 = *(const float4*)(gp);
      ng1 = *(const float4*)(gp + 4*256);
      ng2 = *(const float4*)(gp + 8*256);
      ng3 = *(const float4*)(gp + 12*256);
      ng4 = *(const float4*)(gp + 16*256);
      ng5 = *(const float4*)(gp + 20*256);
      ng6 = *(const float4*)(gp + 24*256);
      ng7 = *(const float4*)(gp + 28*256);
      nx0 = *(const float4*)(x + (size_t)(t0 + xtok) * 512 + kb + 32 + xk8);
      nx1 = *(const float4*)(x + (size_t)(t0 + xtok) * 512 + kb + 32 + xk8 + 4);
    }
    #pragma unroll 4
    for (int k = 0; k < 32; ++k){
      const float4 wv = *(const float4*)&g1s[k][cg << 2];
      const float4 xq0 = *(const float4*)&xs[k][(tg << 4) + 0];
      const float4 xq1 = *(const float4*)&xs[k][(tg << 4) + 4];
      const float4 xq2 = *(const float4*)&xs[k][(tg << 4) + 8];
      const float4 xq3 = *(const float4*)&xs[k][(tg << 4) + 12];
      #define FMA4(T, XV) \
        acc[T][0] = fmaf(XV, wv.x, acc[T][0]); acc[T][1] = fmaf(XV, wv.y, acc[T][1]); \
        acc[T][2] = fmaf(XV, wv.z, acc[T][2]); acc[T][3] = fmaf(XV, wv.w, acc[T][3]);
      FMA4(0,  xq0.x) FMA4(1,  xq0.y) FMA4(2,  xq0.z) FMA4(3,  xq0.w)
      FMA4(4,  xq1.x) FMA4(5,  xq1.y) FMA4(6,  xq1.z) FMA4(7,  xq1.w)
      FMA4(8,  xq2.x) FMA4(9,  xq2.y) FMA4(10, xq2.z) FMA4(11, xq2.w)
      FMA4(12, xq3.x) FMA4(13, xq3.y) FMA4(14, xq3.z) FMA4(15, xq3.w)
      #undef FMA4
    }
    __syncthreads();
  }

  const float4 bias = *(const float4*)(gb1 + (cg << 2));
  float* hp = h + (size_t)(t0 + (tg << 4)) * 256 + (cg << 2);
  #pragma unroll
  for (int t = 0; t < 16; ++t){
    float4 o;
    o.x = fmaxf(acc[t][0] + bias.x, 0.f);
    o.y = fmaxf(acc[t][1] + bias.y, 0.f);
    o.z = fmaxf(acc[t][2] + bias.z, 0.f);
    o.w = fmaxf(acc[t][3] + bias.w, 0.f);
    *(float4*)(hp + (size_t)t * 256) = o;
  }
}

// ---------------------------------------------------------------------------
// Gate2: logits, softmax, top2, re-softmax, block-aggregated scatter.
// Records tpos[token*2 + {0,1}] = (e<<16)|list_pos for the combiner.
// ---------------------------------------------------------------------------
__global__ __launch_bounds__(256, 2)
void gate2_kernel(const float* __restrict__ h, const float* __restrict__ gw2,
                  const float* __restrict__ gb2,
                  int* __restrict__ counts, int* __restrict__ pair_tok,
                  float* __restrict__ pair_w, int* __restrict__ tpos){
  __shared__ float g2s[256 * 9];
  __shared__ int   lcnt[8];
  __shared__ int   lbase[8];
  __shared__ int   lpre[9];
  __shared__ int   ltok[8][256];
  __shared__ float lw[8][256];
  const int tid = threadIdx.x;
  const int t0 = blockIdx.x << 8;

  #pragma unroll
  for (int p = 0; p < 8; ++p){
    int idx = tid + (p << 8);
    g2s[(idx >> 3) * 9 + (idx & 7)] = gw2[idx];
  }
  if (tid < 8) lcnt[tid] = 0;
  __syncthreads();

  const int token = t0 + tid;
  float pl[8];
  #pragma unroll
  for (int e = 0; e < 8; ++e) pl[e] = gb2[e];
  for (int j = 0; j < 64; ++j){
    const float4 hv = *(const float4*)(h + (size_t)token * 256 + (j << 2));
    #pragma unroll
    for (int i = 0; i < 4; ++i){
      const float hx = ((const float*)&hv)[i];
      #pragma unroll
      for (int e = 0; e < 8; ++e)
        pl[e] = fmaf(hx, g2s[((j << 2) + i) * 9 + e], pl[e]);
    }
  }
  float m = pl[0];
  #pragma unroll
  for (int e = 1; e < 8; ++e) m = fmaxf(m, pl[e]);
  float p[8]; float s = 0.f;
  #pragma unroll
  for (int e = 0; e < 8; ++e){ p[e] = expf(pl[e] - m); s += p[e]; }
  float inv = 1.f / s;
  float m1 = -1.f, m2 = -1.f; int i1 = 0, i2 = 0;
  #pragma unroll
  for (int e = 0; e < 8; ++e){
    float pe = p[e] * inv;
    if (pe > m1){ m2 = m1; i2 = i1; m1 = pe; i1 = e; }
    else if (pe > m2){ m2 = pe; i2 = e; }
  }
  float e21 = expf(m2 - m1);
  float w1 = 1.f / (1.f + e21);
  float w2 = 1.f - w1;
  int p1 = atomicAdd(&lcnt[i1], 1); ltok[i1][p1] = token; lw[i1][p1] = w1;
  int p2 = atomicAdd(&lcnt[i2], 1); ltok[i2][p2] = token; lw[i2][p2] = w2;
  __syncthreads();
  if (tid < 8) lbase[tid] = atomicAdd(&counts[tid], lcnt[tid]);
  if (tid == 0){
    lpre[0] = 0;
    #pragma unroll
    for (int e = 0; e < 8; ++e) lpre[e+1] = lpre[e] + lcnt[e];
  }
  __syncthreads();
  tpos[(size_t)token * 2]     = (i1 << 16) + lbase[i1] + p1;
  tpos[(size_t)token * 2 + 1] = (i2 << 16) + lbase[i2] + p2;
  const int total = lpre[8];
  for (int idx = tid; idx < total; idx += 256){
    int e = 0;
    #pragma unroll
    for (int q = 0; q < 7; ++q) e += (idx >= lpre[q + 1]) ? 1 : 0;
    const int i = idx - lpre[e];
    const int dst = (e << 16) + lbase[e] + i;
    pair_tok[dst] = ltok[e][i];
    pair_w[dst]   = lw[e][i];
  }
}

// ---------------------------------------------------------------------------
// Scan: chunk offsets (128-token chunks) + exact token prefix offsets.
// ---------------------------------------------------------------------------
__global__ void scan_kernel(const int* __restrict__ counts, int* __restrict__ offs,
                            int* __restrict__ toffs){
  if (threadIdx.x == 0){
    int o = 0, t = 0;
    #pragma unroll
    for (int e = 0; e < 8; ++e){
      offs[e] = o; o += (counts[e] + 127) >> 7;
      toffs[e] = t; t += counts[e];
    }
    offs[8] = o; toffs[8] = t;
  }
}

// ---------------------------------------------------------------------------
// eg1: h[seq][1024] = gelu(gather(x) @ we1 + be1), bf16.
// 32KB LDS, 4 blocks/CU, XCD-chunked swizzle, swapped MFMA operands,
// tanh-gelu epilogue. (R13-verified)
// ---------------------------------------------------------------------------
__global__ __launch_bounds__(256, 4)
void eg1_kernel(const unsigned short* __restrict__ xbf,
                const unsigned short* __restrict__ we1T,   // [E][1024][512]
                const float* __restrict__ be1,
                const int* __restrict__ counts, const int* __restrict__ offs,
                const int* __restrict__ toffs, const int* __restrict__ pair_tok,
                unsigned short* __restrict__ h){
  const int g = (blockIdx.x & 7) * 1032 + (blockIdx.x >> 3);
  const int chunk = g >> 3, nt = g & 7;
  if (chunk >= offs[8]) return;
  int e = 0;
  #pragma unroll
  for (int q = 0; q < 7; ++q) e += (chunk >= offs[q+1]) ? 1 : 0;
  const int cnt = counts[e];
  const int base = (chunk - offs[e]) << 7;
  const int n0 = nt << 7;
  const int tid = threadIdx.x;
  const int lane = tid & 63;
  const int wv = tid >> 6;
  const int wr = wv >> 1, wc = wv & 1;
  const int lrow = lane & 15, kgrp = lane >> 4;

  __shared__ char lds[32768];
  char* const As = lds;
  char* const Bs = lds + 16384;

  const int srow = tid >> 3;
  const int sdelta = ((tid & 7) << 4) ^ ((srow & 7) << 4);
  unsigned aoff[4];
  #pragma unroll
  for (int i = 0; i < 4; ++i){
    int rr = base + srow + (i << 5);
    int tok = (rr < cnt) ? pair_tok[(e << 16) + rr] : 0;
    aoff[i] = ((unsigned)tok) << 10;
  }
  const char* const xb  = (const char*)xbf;
  const char* const w1b = (const char*)we1T + ((size_t)e << 20);

  f32x4 acc[4][4];                       // [hcol-frag][token-frag]
  #pragma unroll
  for (int i = 0; i < 4; ++i)
    #pragma unroll
    for (int j = 0; j < 4; ++j) acc[i][j] = (f32x4)0.f;

  const int sw = (lrow & 7) << 4;
  for (int kb = 0; kb < 8; ++kb){
    #pragma unroll
    for (int i = 0; i < 4; ++i)
      gload16(xb + aoff[i] + (kb << 7) + sdelta, As + (tid << 4) + (i << 12));
    #pragma unroll
    for (int i = 0; i < 4; ++i)
      gload16(w1b + (size_t)(n0 + srow + (i << 5)) * 1024 + (kb << 7) + sdelta,
              Bs + (tid << 4) + (i << 12));
    __syncthreads();
    #pragma unroll
    for (int s = 0; s < 2; ++s){
      const int kbyte = ((s << 6) + (kgrp << 4)) ^ sw;
      bf16x8 af[4], bf[4];
      #pragma unroll
      for (int f = 0; f < 4; ++f){
        af[f] = *(const bf16x8*)(As + ((wr << 6) + (f << 4) + lrow) * 128 + kbyte);
        bf[f] = *(const bf16x8*)(Bs + ((wc << 6) + (f << 4) + lrow) * 128 + kbyte);
      }
      #pragma unroll
      for (int fb = 0; fb < 4; ++fb)
        #pragma unroll
        for (int fa = 0; fa < 4; ++fa)
          acc[fb][fa] = __builtin_amdgcn_mfma_f32_16x16x32_bf16(bf[fb], af[fa], acc[fb][fa], 0, 0, 0);
    }
    __syncthreads();
  }

  const int hrow0 = toffs[e] + base;
  float4 bias4[4];
  #pragma unroll
  for (int fb = 0; fb < 4; ++fb)
    bias4[fb] = *(const float4*)(be1 + (e << 10) + n0 + (wc << 6) + (fb << 4) + (kgrp << 2));
  #pragma unroll
  for (int fa = 0; fa < 4; ++fa){
    const int tl = (wr << 6) + (fa << 4) + lrow;
    if (base + tl < cnt){
      unsigned short* hp = h + (size_t)(hrow0 + tl) * 1024 + n0 + (wc << 6) + (kgrp << 2);
      #pragma unroll
      for (int fb = 0; fb < 4; ++fb){
        ushort4 o;
        o.x = f2bf(gelu_fast(acc[fb][fa][0] + bias4[fb].x));
        o.y = f2bf(gelu_fast(acc[fb][fa][1] + bias4[fb].y));
        o.z = f2bf(gelu_fast(acc[fb][fa][2] + bias4[fb].z));
        o.w = f2bf(gelu_fast(acc[fb][fa][3] + bias4[fb].w));
        *(ushort4*)(hp + (fb << 4)) = o;
      }
    }
  }
}

// ---------------------------------------------------------------------------
// eg2 (swapped operands): y = h @ we2 + be2 -> ybuf (bf16, no atomics).
// Fallback: atomic accumulate into out. (R13-verified)
// ---------------------------------------------------------------------------
__global__ __launch_bounds__(256, 4)
void eg2_kernel(const unsigned short* __restrict__ h,
                const unsigned short* __restrict__ we2T,   // [E][512][1024]
                const float* __restrict__ be2,
                const int* __restrict__ counts, const int* __restrict__ offs,
                const int* __restrict__ toffs, const int* __restrict__ pair_tok,
                const float* __restrict__ pair_w,
                unsigned short* __restrict__ ybuf,         // may be null
                float* __restrict__ out){
  const int g = (blockIdx.x & 7) * 516 + (blockIdx.x >> 3);
  const int chunk = g >> 2, nt = g & 3;
  if (chunk >= offs[8]) return;
  int e = 0;
  #pragma unroll
  for (int q = 0; q < 7; ++q) e += (chunk >= offs[q+1]) ? 1 : 0;
  const int cnt = counts[e];
  const int base = (chunk - offs[e]) << 7;
  const int n0 = nt << 7;
  const int tid = threadIdx.x;
  const int lane = tid & 63;
  const int wv = tid >> 6;
  const int wr = wv >> 1, wc = wv & 1;
  const int lrow = lane & 15, kgrp = lane >> 4;

  __shared__ char lds[32768];
  char* const As = lds;
  char* const Bs = lds + 16384;

  const int srow = tid >> 3;
  const int sdelta = ((tid & 7) << 4) ^ ((srow & 7) << 4);
  const char* const hb  = (const char*)h + (size_t)(toffs[e] + base) * 2048;
  const char* const w2b = (const char*)we2T + ((size_t)e << 20);

  f32x4 acc[4][4];                       // [outcol-frag][token-frag]
  #pragma unroll
  for (int i = 0; i < 4; ++i)
    #pragma unroll
    for (int j = 0; j < 4; ++j) acc[i][j] = (f32x4)0.f;

  const int sw = (lrow & 7) << 4;
  for (int kb = 0; kb < 16; ++kb){
    #pragma unroll
    for (int i = 0; i < 4; ++i)
      gload16(hb + (size_t)(srow + (i << 5)) * 2048 + (kb << 7) + sdelta,
              As + (tid << 4) + (i << 12));
    #pragma unroll
    for (int i = 0; i < 4; ++i)
      gload16(w2b + (size_t)(n0 + srow + (i << 5)) * 2048 + (kb << 7) + sdelta,
              Bs + (tid << 4) + (i << 12));
    __syncthreads();
    #pragma unroll
    for (int s = 0; s < 2; ++s){
      const int kbyte = ((s << 6) + (kgrp << 4)) ^ sw;
      bf16x8 af[4], bf[4];
      #pragma unroll
      for (int f = 0; f < 4; ++f){
        af[f] = *(const bf16x8*)(As + ((wr << 6) + (f << 4) + lrow) * 128 + kbyte);
        bf[f] = *(const bf16x8*)(Bs + ((wc << 6) + (f << 4) + lrow) * 128 + kbyte);
      }
      #pragma unroll
      for (int fb = 0; fb < 4; ++fb)
        #pragma unroll
        for (int fa = 0; fa < 4; ++fa)
          acc[fb][fa] = __builtin_amdgcn_mfma_f32_16x16x32_bf16(bf[fb], af[fa], acc[fb][fa], 0, 0, 0);
    }
    __syncthreads();
  }

  float4 bias4[4];
  #pragma unroll
  for (int fb = 0; fb < 4; ++fb)
    bias4[fb] = *(const float4*)(be2 + (e << 9) + n0 + (wc << 6) + (fb << 4) + (kgrp << 2));

  if (ybuf){
    const int yrow0 = toffs[e] + base;
    #pragma unroll
    for (int fa = 0; fa < 4; ++fa){
      const int tl = (wr << 6) + (fa << 4) + lrow;
      if (base + tl < cnt){
        unsigned short* yp = ybuf + (size_t)(yrow0 + tl) * 512 + n0 + (wc << 6) + (kgrp << 2);
        #pragma unroll
        for (int fb = 0; fb < 4; ++fb){
          ushort4 o;
          o.x = f2bf(acc[fb][fa][0] + bias4[fb].x);
          o.y = f2bf(acc[fb][fa][1] + bias4[fb].y);
          o.z = f2bf(acc[fb][fa][2] + bias4[fb].z);
          o.w = f2bf(acc[fb][fa][3] + bias4[fb].w);
          *(ushort4*)(yp + (fb << 4)) = o;
        }
      }
    }
  } else {
    #pragma unroll
    for (int fa = 0; fa < 4; ++fa){
      const int tl = (wr << 6) + (fa << 4) + lrow;
      const int r = base + tl;
      if (r < cnt){
        const int tok = pair_tok[(e << 16) + r];
        const float wgt = pair_w[(e << 16) + r];
        float* const orow = out + (size_t)tok * 512 + n0 + (wc << 6) + (kgrp << 2);
        #pragma unroll
        for (int fb = 0; fb < 4; ++fb){
          atomicAdd(orow + (fb << 4) + 0, wgt * (acc[fb][fa][0] + bias4[fb].x));
          atomicAdd(orow + (fb << 4) + 1, wgt * (acc[fb][fa][1] + bias4[fb].y));
          atomicAdd(orow + (fb << 4) + 2, wgt * (acc[fb][fa][2] + bias4[fb].z));
          atomicAdd(orow + (fb << 4) + 3, wgt * (acc[fb][fa][3] + bias4[fb].w));
        }
      }
    }
  }
}

// ---------------------------------------------------------------------------
// Combine: out[t] = w0 * y[seq0] + w1 * y[seq1].
// ---------------------------------------------------------------------------
__global__ __launch_bounds__(256, 8)
void combine_kernel(const unsigned short* __restrict__ ybuf,
                    const int* __restrict__ tpos, const int* __restrict__ toffs,
                    const float* __restrict__ pair_w,
                    float* __restrict__ out){
  const int wg = threadIdx.x >> 6;
  const int lane = threadIdx.x & 63;
  for (int t = (blockIdx.x << 2) + wg; t < 65536; t += 4096 * 4){
    const int d0 = tpos[(size_t)t * 2];
    const int d1 = tpos[(size_t)t * 2 + 1];
    const int seq0 = toffs[d0 >> 16] + (d0 & 0xFFFF);
    const int seq1 = toffs[d1 >> 16] + (d1 & 0xFFFF);
    const float w0 = pair_w[d0];
    const float w1 = pair_w[d1];
    const bf16x8 a = *(const bf16x8*)(ybuf + (size_t)seq0 * 512 + (lane << 3));
    const bf16x8 b = *(const bf16x8*)(ybuf + (size_t)seq1 * 512 + (lane << 3));
    float4 o0, o1;
    o0.x = w0*bf2f((unsigned short)a[0]) + w1*bf2f((unsigned short)b[0]);
    o0.y = w0*bf2f((unsigned short)a[1]) + w1*bf2f((unsigned short)b[1]);
    o0.z = w0*bf2f((unsigned short)a[2]) + w1*bf2f((unsigned short)b[2]);
    o0.w = w0*bf2f((unsigned short)a[3]) + w1*bf2f((unsigned short)b[3]);
    o1.x = w0*bf2f((unsigned short)a[4]) + w1*bf2f((unsigned short)b[4]);
    o1.y = w0*bf2f((unsigned short)a[5]) + w1*bf2f((unsigned short)b[5]);
    o1.z = w0*bf2f((unsigned short)a[6]) + w1*bf2f((unsigned short)b[6]);
    o1.w = w0*bf2f((unsigned short)a[7]) + w1*bf2f((unsigned short)b[7]);
    float* op = out + (size_t)t * 512 + (lane << 3);
    *(float4*)op = o0;
    *(float4*)(op + 4) = o1;
  }
}

// ---------------------------------------------------------------------------
extern "C" void kernel_launch(void* const* d_in, const int* in_sizes, int n_in,
                              void* d_out, int out_size, void* d_ws, size_t ws_size,
                              hipStream_t stream){
  const float* x   = (const float*)d_in[0];
  const float* gw1 = (const float*)d_in[1];
  const float* gb1 = (const float*)d_in[2];
  const float* gw2 = (const float*)d_in[3];
  const float* gb2 = (const float*)d_in[4];
  const float* we1 = (const float*)d_in[5];
  const float* be1 = (const float*)d_in[6];
  const float* we2 = (const float*)d_in[7];
  const float* be2 = (const float*)d_in[8];
  float* out = (float*)d_out;

  char* ws = (char*)d_ws;
  const size_t MiB = 1024 * 1024;
  unsigned short* we1T = (unsigned short*)(ws);                 // 8 MiB
  unsigned short* we2T = (unsigned short*)(ws + 8 * MiB);       // 8 MiB
  int*   pair_tok = (int*)  (ws + 16 * MiB);                    // 2 MiB
  float* pair_w   = (float*)(ws + 18 * MiB);                    // 2 MiB
  int*   counts   = (int*)  (ws + 20 * MiB);                    // 64 B
  int*   offs     = (int*)  (ws + 20 * MiB + 256);              // 64 B
  int*   toffs    = (int*)  (ws + 20 * MiB + 512);              // 64 B
  int*   tpos     = (int*)  (ws + 20 * MiB + 4096);             // 512 KiB
  unsigned short* xbf  = (unsigned short*)(ws + 21 * MiB);      // 64 MiB
  float* ghuf          = (float*)(ws + 85 * MiB);               // 64 MiB (gate h)
  unsigned short* hexp = (unsigned short*)(ws + 85 * MiB);      // 256 MiB, aliases ghuf
  unsigned short* ybuf = (unsigned short*)(ws + 341 * MiB);     // 128 MiB
  const bool have_y = ws_size >= 470 * MiB;

  if (!have_y)
    hipMemsetAsync(d_out, 0, (size_t)out_size * sizeof(float), stream);
  hipMemsetAsync(counts, 0, 256, stream);

  hipLaunchKernelGGL(transpose_cvt_kernel, dim3(1024), dim3(256), 0, stream,
                     we1, we1T, 512, 1024);
  hipLaunchKernelGGL(transpose_cvt_kernel, dim3(1024), dim3(256), 0, stream,
                     we2, we2T, 1024, 512);
  hipLaunchKernelGGL(gate_gemm1_kernel, dim3(1024), dim3(256), 0, stream,
                     x, gw1, gb1, ghuf, xbf);
  hipLaunchKernelGGL(gate2_kernel, dim3(256), dim3(256), 0, stream,
                     ghuf, gw2, gb2, counts, pair_tok, pair_w, tpos);
  hipLaunchKernelGGL(scan_kernel, dim3(1), dim3(64), 0, stream, counts, offs, toffs);

  hipLaunchKernelGGL(eg1_kernel, dim3(8256), dim3(256), 0, stream,
                     xbf, we1T, be1, counts, offs, toffs, pair_tok, hexp);
  hipLaunchKernelGGL(eg2_kernel, dim3(4128), dim3(256), 0, stream,
                     hexp, we2T, be2, counts, offs, toffs, pair_tok, pair_w,
                     have_y ? ybuf : (unsigned short*)nullptr, out);
  if (have_y)
    hipLaunchKernelGGL(combine_kernel, dim3(4096), dim3(256), 0, stream,
                       ybuf, tpos, toffs, pair_w, out);
}